// Round 1
// baseline (3169.099 us; speedup 1.0000x reference)
//
#include <hip/hip_runtime.h>
#include <hip/hip_bf16.h>

#define SEQ     4096
#define HIDDEN  640
#define HDIM    80
#define NH      8
#define NKV     2
#define NREP    4
#define WINDOW  512
#define SINK    4

// ---------------------------------------------------------------------------
// Generic fp32 tiled GEMM: C[M,N] = A[M,K] @ B[K,N]
// A row-major (lda), B row-major (ldb=N), C row-major (ldc).
// BM=BN=64, BK=16, 256 threads, 4x4 per thread. M % 64 == 0, K % 16 == 0.
// ---------------------------------------------------------------------------
__global__ __launch_bounds__(256) void gemm_f32(
    const float* __restrict__ A, const float* __restrict__ B,
    float* __restrict__ C, int M, int N, int K, int lda, int ldc)
{
    __shared__ float As[16][65];
    __shared__ float Bs[16][65];

    const int tid = threadIdx.x;
    const int tx = tid & 15;        // 0..15 -> N direction
    const int ty = tid >> 4;        // 0..15 -> M direction
    const int m0 = blockIdx.y * 64;
    const int n0 = blockIdx.x * 64;

    float acc[4][4] = {};

    for (int k0 = 0; k0 < K; k0 += 16) {
        // A tile: 64 rows x 16 cols. lane: kk = tid&15, m = tid>>4 (+16*p)
        #pragma unroll
        for (int p = 0; p < 4; ++p) {
            int m  = (tid >> 4) + p * 16;
            int kk = tid & 15;
            As[kk][m] = A[(size_t)(m0 + m) * lda + k0 + kk];
        }
        // B tile: 16 rows x 64 cols. lane: c = tid&63, r = tid>>6 (+4*p)
        #pragma unroll
        for (int p = 0; p < 4; ++p) {
            int r = (tid >> 6) + p * 4;
            int c = tid & 63;
            int n = n0 + c;
            Bs[r][c] = (n < N) ? B[(size_t)(k0 + r) * N + n] : 0.0f;
        }
        __syncthreads();

        #pragma unroll
        for (int kk = 0; kk < 16; ++kk) {
            float a[4], b[4];
            #pragma unroll
            for (int mm = 0; mm < 4; ++mm) a[mm] = As[kk][ty * 4 + mm];
            #pragma unroll
            for (int nn = 0; nn < 4; ++nn) b[nn] = Bs[kk][tx * 4 + nn];
            #pragma unroll
            for (int mm = 0; mm < 4; ++mm)
                #pragma unroll
                for (int nn = 0; nn < 4; ++nn)
                    acc[mm][nn] = fmaf(a[mm], b[nn], acc[mm][nn]);
        }
        __syncthreads();
    }

    #pragma unroll
    for (int mm = 0; mm < 4; ++mm) {
        int m = m0 + ty * 4 + mm;
        #pragma unroll
        for (int nn = 0; nn < 4; ++nn) {
            int n = n0 + tx * 4 + nn;
            if (n < N) C[(size_t)m * ldc + n] = acc[mm][nn];
        }
    }
}

// ---------------------------------------------------------------------------
// RMSNorm + RoPE for Q heads (hh in 0..7) and K heads (hh in 8..9).
// One 128-thread block per (row, head). qkv: [SEQ][960] (q 0..639, k 640..799).
// qrot: [SEQ][640], krot: [SEQ][160].
// ---------------------------------------------------------------------------
__global__ __launch_bounds__(128) void norm_rope_kernel(
    const float* __restrict__ qkv, const float* __restrict__ cosb,
    const float* __restrict__ sinb, const float* __restrict__ qw,
    const float* __restrict__ kw, float* __restrict__ qrot,
    float* __restrict__ krot)
{
    const int row = blockIdx.x;
    const int hh  = blockIdx.y;          // 0..9
    const int tid = threadIdx.x;

    __shared__ float buf[HDIM];
    __shared__ float red[2];

    const float* src;
    const float* w;
    float* dst;
    if (hh < NH) {
        src = qkv + (size_t)row * 960 + hh * HDIM;
        w   = qw;
        dst = qrot + (size_t)row * (NH * HDIM) + hh * HDIM;
    } else {
        int kvh = hh - NH;
        src = qkv + (size_t)row * 960 + HIDDEN + kvh * HDIM;
        w   = kw;
        dst = krot + (size_t)row * (NKV * HDIM) + kvh * HDIM;
    }

    float v = (tid < HDIM) ? src[tid] : 0.0f;
    float sq = v * v;
    #pragma unroll
    for (int off = 32; off; off >>= 1) sq += __shfl_down(sq, off);
    if ((tid & 63) == 0) red[tid >> 6] = sq;
    __syncthreads();
    float rms = rsqrtf((red[0] + red[1]) * (1.0f / HDIM) + 1e-5f);
    if (tid < HDIM) buf[tid] = v * rms * w[tid];
    __syncthreads();

    if (tid < HDIM / 2) {
        float c  = cosb[(size_t)row * (HDIM / 2) + tid];
        float s  = sinb[(size_t)row * (HDIM / 2) + tid];
        float ve = buf[2 * tid];
        float vo = buf[2 * tid + 1];
        dst[2 * tid]     = ve * c - vo * s;
        dst[2 * tid + 1] = vo * c + ve * s;
    }
}

// ---------------------------------------------------------------------------
// Windowed attention with sink tokens. One 320-thread block per (query i, head h).
// q: [SEQ][640] (roped), k: [SEQ][160] (roped), qkv: v at cols 800..959,
// output written into qkv cols 0..639 (Q columns are dead after norm_rope).
// ---------------------------------------------------------------------------
__global__ __launch_bounds__(320) void attn_kernel(
    const float* __restrict__ q, const float* __restrict__ k,
    float* qkv)
{
    const int i   = blockIdx.x;      // query position
    const int h   = blockIdx.y;      // head
    const int kvh = h >> 2;          // h / NREP
    const int tid = threadIdx.x;

    __shared__ float qs[HDIM];
    __shared__ float sc[WINDOW + SINK];   // 516
    __shared__ float redmax[5], redsum[5];
    __shared__ float pv[4][HDIM];
    __shared__ float bmax, bsum;

    if (tid < HDIM) qs[tid] = q[(size_t)i * (NH * HDIM) + h * HDIM + tid];

    int lo = i - (WINDOW - 1);
    if (lo < 0) lo = 0;
    const int s_end = (lo < SINK) ? lo : SINK;           // sinks strictly below window
    const int n = s_end + (i - lo) + 1;                  // total allowed keys
    __syncthreads();

    const float scale = 0.11180339887498948f;            // 1/sqrt(80)

    for (int t = tid; t < n; t += 320) {
        int j = (t < s_end) ? t : lo + (t - s_end);
        const float* kr = k + (size_t)j * (NKV * HDIM) + kvh * HDIM;
        float acc = 0.0f;
        #pragma unroll
        for (int d = 0; d < HDIM; ++d) acc = fmaf(qs[d], kr[d], acc);
        sc[t] = acc * scale;
    }
    __syncthreads();

    // ---- block max ----
    float m = -3.0e38f;
    for (int t = tid; t < n; t += 320) m = fmaxf(m, sc[t]);
    #pragma unroll
    for (int off = 32; off; off >>= 1) m = fmaxf(m, __shfl_down(m, off));
    if ((tid & 63) == 0) redmax[tid >> 6] = m;
    __syncthreads();
    if (tid == 0) {
        float r = redmax[0];
        for (int w = 1; w < 5; ++w) r = fmaxf(r, redmax[w]);
        bmax = r;
    }
    __syncthreads();
    m = bmax;

    // ---- exp + block sum ----
    float ssum = 0.0f;
    for (int t = tid; t < n; t += 320) {
        float e = __expf(sc[t] - m);
        sc[t] = e;
        ssum += e;
    }
    #pragma unroll
    for (int off = 32; off; off >>= 1) ssum += __shfl_down(ssum, off);
    if ((tid & 63) == 0) redsum[tid >> 6] = ssum;
    __syncthreads();
    if (tid == 0) {
        float r = 0.0f;
        for (int w = 0; w < 5; ++w) r += redsum[w];
        bsum = r;
    }
    __syncthreads();
    const float inv = 1.0f / bsum;

    // ---- PV: 4 groups of 80 threads ----
    const int g = tid / HDIM;        // 0..3
    const int d = tid - g * HDIM;    // 0..79
    {
        float acc = 0.0f;
        for (int t = g; t < n; t += 4) {
            int j = (t < s_end) ? t : lo + (t - s_end);
            acc = fmaf(sc[t], qkv[(size_t)j * 960 + 800 + kvh * HDIM + d], acc);
        }
        pv[g][d] = acc;
    }
    __syncthreads();

    if (tid < HDIM) {
        float r = (pv[0][tid] + pv[1][tid] + pv[2][tid] + pv[3][tid]) * inv;
        qkv[(size_t)i * 960 + h * HDIM + tid] = r;   // attn output into dead Q cols
    }
}

// ---------------------------------------------------------------------------
extern "C" void kernel_launch(void* const* d_in, const int* in_sizes, int n_in,
                              void* d_out, int out_size, void* d_ws, size_t ws_size,
                              hipStream_t stream)
{
    const float* x    = (const float*)d_in[0];
    const float* cosb = (const float*)d_in[1];
    const float* sinb = (const float*)d_in[2];
    const float* Wq   = (const float*)d_in[3];
    const float* Wk   = (const float*)d_in[4];
    const float* Wv   = (const float*)d_in[5];
    const float* Wo   = (const float*)d_in[6];
    const float* qw   = (const float*)d_in[7];
    const float* kw   = (const float*)d_in[8];
    float* out = (float*)d_out;

    float* ws   = (float*)d_ws;
    float* qkv  = ws;                                  // [SEQ][960]
    float* qrot = qkv  + (size_t)SEQ * 960;            // [SEQ][640]
    float* krot = qrot + (size_t)SEQ * (NH * HDIM);    // [SEQ][160]
    // total ws use: (960+640+160)*4096 floats = 28.8 MB

    dim3 blk(256);

    // QKV projections into the fused panel
    gemm_f32<<<dim3(HIDDEN / 64, SEQ / 64), blk, 0, stream>>>(
        x, Wq, qkv, SEQ, HIDDEN, HIDDEN, HIDDEN, 960);
    gemm_f32<<<dim3((NKV * HDIM + 63) / 64, SEQ / 64), blk, 0, stream>>>(
        x, Wk, qkv + HIDDEN, SEQ, NKV * HDIM, HIDDEN, HIDDEN, 960);
    gemm_f32<<<dim3((NKV * HDIM + 63) / 64, SEQ / 64), blk, 0, stream>>>(
        x, Wv, qkv + HIDDEN + NKV * HDIM, SEQ, NKV * HDIM, HIDDEN, HIDDEN, 960);

    // RMSNorm + RoPE (8 Q heads + 2 K heads)
    norm_rope_kernel<<<dim3(SEQ, NH + NKV), dim3(128), 0, stream>>>(
        qkv, cosb, sinb, qw, kw, qrot, krot);

    // Windowed attention; output overwrites qkv cols 0..639
    attn_kernel<<<dim3(SEQ, NH), dim3(320), 0, stream>>>(qrot, krot, qkv);

    // Output projection: (attn out, lda=960) @ Wo -> d_out
    gemm_f32<<<dim3(HIDDEN / 64, SEQ / 64), blk, 0, stream>>>(
        qkv, Wo, out, SEQ, HIDDEN, HIDDEN, 960, HIDDEN);
}

// Round 2
// 480.860 us; speedup vs baseline: 6.5905x; 6.5905x over previous
//
#include <hip/hip_runtime.h>
#include <hip/hip_bf16.h>

#define SEQ     4096
#define HIDDEN  640
#define HDIM    80
#define NH      8
#define NKV     2
#define NREP    4
#define WINDOW  512
#define SINK    4
#define BQ      64
#define BK      64

// ---------------------------------------------------------------------------
// Generic fp32 tiled GEMM: C[M,N] = A[M,K] @ B[K,N]
// ---------------------------------------------------------------------------
__global__ __launch_bounds__(256) void gemm_f32(
    const float* __restrict__ A, const float* __restrict__ B,
    float* __restrict__ C, int M, int N, int K, int lda, int ldc)
{
    __shared__ float As[16][65];
    __shared__ float Bs[16][65];

    const int tid = threadIdx.x;
    const int tx = tid & 15;
    const int ty = tid >> 4;
    const int m0 = blockIdx.y * 64;
    const int n0 = blockIdx.x * 64;

    float acc[4][4] = {};

    for (int k0 = 0; k0 < K; k0 += 16) {
        #pragma unroll
        for (int p = 0; p < 4; ++p) {
            int m  = (tid >> 4) + p * 16;
            int kk = tid & 15;
            As[kk][m] = A[(size_t)(m0 + m) * lda + k0 + kk];
        }
        #pragma unroll
        for (int p = 0; p < 4; ++p) {
            int r = (tid >> 6) + p * 4;
            int c = tid & 63;
            int n = n0 + c;
            Bs[r][c] = (n < N) ? B[(size_t)(k0 + r) * N + n] : 0.0f;
        }
        __syncthreads();

        #pragma unroll
        for (int kk = 0; kk < 16; ++kk) {
            float a[4], b[4];
            #pragma unroll
            for (int mm = 0; mm < 4; ++mm) a[mm] = As[kk][ty * 4 + mm];
            #pragma unroll
            for (int nn = 0; nn < 4; ++nn) b[nn] = Bs[kk][tx * 4 + nn];
            #pragma unroll
            for (int mm = 0; mm < 4; ++mm)
                #pragma unroll
                for (int nn = 0; nn < 4; ++nn)
                    acc[mm][nn] = fmaf(a[mm], b[nn], acc[mm][nn]);
        }
        __syncthreads();
    }

    #pragma unroll
    for (int mm = 0; mm < 4; ++mm) {
        int m = m0 + ty * 4 + mm;
        #pragma unroll
        for (int nn = 0; nn < 4; ++nn) {
            int n = n0 + tx * 4 + nn;
            if (n < N) C[(size_t)m * ldc + n] = acc[mm][nn];
        }
    }
}

// ---------------------------------------------------------------------------
// RMSNorm + RoPE (Q heads 0..7, K heads 8..9)
// ---------------------------------------------------------------------------
__global__ __launch_bounds__(128) void norm_rope_kernel(
    const float* __restrict__ qkv, const float* __restrict__ cosb,
    const float* __restrict__ sinb, const float* __restrict__ qw,
    const float* __restrict__ kw, float* __restrict__ qrot,
    float* __restrict__ krot)
{
    const int row = blockIdx.x;
    const int hh  = blockIdx.y;
    const int tid = threadIdx.x;

    __shared__ float buf[HDIM];
    __shared__ float red[2];

    const float* src;
    const float* w;
    float* dst;
    if (hh < NH) {
        src = qkv + (size_t)row * 960 + hh * HDIM;
        w   = qw;
        dst = qrot + (size_t)row * (NH * HDIM) + hh * HDIM;
    } else {
        int kvh = hh - NH;
        src = qkv + (size_t)row * 960 + HIDDEN + kvh * HDIM;
        w   = kw;
        dst = krot + (size_t)row * (NKV * HDIM) + kvh * HDIM;
    }

    float v = (tid < HDIM) ? src[tid] : 0.0f;
    float sq = v * v;
    #pragma unroll
    for (int off = 32; off; off >>= 1) sq += __shfl_down(sq, off);
    if ((tid & 63) == 0) red[tid >> 6] = sq;
    __syncthreads();
    float rms = rsqrtf((red[0] + red[1]) * (1.0f / HDIM) + 1e-5f);
    if (tid < HDIM) buf[tid] = v * rms * w[tid];
    __syncthreads();

    if (tid < HDIM / 2) {
        float c  = cosb[(size_t)row * (HDIM / 2) + tid];
        float s  = sinb[(size_t)row * (HDIM / 2) + tid];
        float ve = buf[2 * tid];
        float vo = buf[2 * tid + 1];
        dst[2 * tid]     = ve * c - vo * s;
        dst[2 * tid + 1] = vo * c + ve * s;
    }
}

// ---------------------------------------------------------------------------
// Flash-style windowed attention with sinks.
// One 256-thread block per (64-query tile, head). Iterates key tiles of 64.
// Q,K staged d-major in LDS (pad +1, conflict-free scalar reads),
// V row-major (stride 84), P via LDS for the PV transpose.
// Output written into qkv cols 0..639 (dead Q columns).
// ---------------------------------------------------------------------------
__global__ __launch_bounds__(256) void flash_attn(
    const float* __restrict__ q, const float* __restrict__ k,
    float* __restrict__ qkv)
{
    const int i0  = blockIdx.x * BQ;
    const int h   = blockIdx.y;
    const int kvh = h >> 2;
    const int tid = threadIdx.x;
    const int tx  = tid & 15;
    const int ty  = tid >> 4;

    __shared__ float Qs[HDIM][BQ + 1];   // d-major, 20800 B
    __shared__ float Ks[HDIM][BK + 1];   // d-major, 20800 B
    __shared__ float Vs[BK][HDIM + 4];   // row-major stride 84, 21504 B
    __shared__ float Ps[BQ][BK + 1];     // 16640 B   (total 79744 B -> 2 blk/CU)

    const float scale = 0.11180339887498948f;  // 1/sqrt(80)

    // ---- stage Q (pre-scaled), transposed to d-major ----
    #pragma unroll
    for (int p = 0; p < 5; ++p) {
        int idx = tid + 256 * p;          // 0..1279 = 64 rows x 20 float4
        int qi  = idx / 20;
        int c4  = idx % 20;
        const float4 v = *(const float4*)&q[(size_t)(i0 + qi) * (NH * HDIM) + h * HDIM + 4 * c4];
        Qs[4 * c4 + 0][qi] = v.x * scale;
        Qs[4 * c4 + 1][qi] = v.y * scale;
        Qs[4 * c4 + 2][qi] = v.z * scale;
        Qs[4 * c4 + 3][qi] = v.w * scale;
    }

    float m_i[4], l_i[4], o[4][5];
    #pragma unroll
    for (int mm = 0; mm < 4; ++mm) {
        m_i[mm] = -1e30f;
        l_i[mm] = 0.0f;
        #pragma unroll
        for (int dd = 0; dd < 5; ++dd) o[mm][dd] = 0.0f;
    }

    const int w_lo   = i0 - (WINDOW - 1);
    const int w_tile = (w_lo <= 0) ? 0 : (w_lo & ~(BK - 1));
    const int n_win  = (i0 - w_tile) / BK + 1;
    const int n_tiles = n_win + ((w_tile > 0) ? 1 : 0);

    for (int t = 0; t < n_tiles; ++t) {
        const int j0 = (t < n_win) ? (w_tile + t * BK) : 0;   // last tile = sinks

        __syncthreads();   // protect LDS from previous iteration's readers

        // ---- stage K (transposed) and V (row-major) ----
        #pragma unroll
        for (int p = 0; p < 5; ++p) {
            int idx = tid + 256 * p;
            int kj  = idx / 20;
            int c4  = idx % 20;
            const float4 kv4 = *(const float4*)&k[(size_t)(j0 + kj) * (NKV * HDIM) + kvh * HDIM + 4 * c4];
            Ks[4 * c4 + 0][kj] = kv4.x;
            Ks[4 * c4 + 1][kj] = kv4.y;
            Ks[4 * c4 + 2][kj] = kv4.z;
            Ks[4 * c4 + 3][kj] = kv4.w;
            const float4 vv4 = *(const float4*)&qkv[(size_t)(j0 + kj) * 960 + 800 + kvh * HDIM + 4 * c4];
            *(float4*)&Vs[kj][4 * c4] = vv4;
        }
        __syncthreads();

        // ---- S = Q K^T  (4x4 per thread) ----
        float s[4][4] = {};
        #pragma unroll 2
        for (int d = 0; d < HDIM; ++d) {
            float a[4], b[4];
            #pragma unroll
            for (int mm = 0; mm < 4; ++mm) a[mm] = Qs[d][4 * ty + mm];
            #pragma unroll
            for (int nn = 0; nn < 4; ++nn) b[nn] = Ks[d][4 * tx + nn];
            #pragma unroll
            for (int mm = 0; mm < 4; ++mm)
                #pragma unroll
                for (int nn = 0; nn < 4; ++nn)
                    s[mm][nn] = fmaf(a[mm], b[nn], s[mm][nn]);
        }

        // ---- mask (skip for interior full tiles) ----
        const bool full = (j0 >= i0 - 448) && (j0 <= i0 - 64);
        if (!full) {
            #pragma unroll
            for (int mm = 0; mm < 4; ++mm) {
                int i = i0 + 4 * ty + mm;
                #pragma unroll
                for (int nn = 0; nn < 4; ++nn) {
                    int j = j0 + 4 * tx + nn;
                    bool allowed = (j <= i) && ((j >= i - (WINDOW - 1)) || (j < SINK));
                    if (!allowed) s[mm][nn] = -1e30f;
                }
            }
        }

        // ---- online softmax ----
        #pragma unroll
        for (int mm = 0; mm < 4; ++mm) {
            float rmax = fmaxf(fmaxf(s[mm][0], s[mm][1]), fmaxf(s[mm][2], s[mm][3]));
            #pragma unroll
            for (int off = 8; off; off >>= 1)
                rmax = fmaxf(rmax, __shfl_xor(rmax, off, 16));
            float Mnew  = fmaxf(m_i[mm], rmax);
            float alpha = __expf(m_i[mm] - Mnew);
            m_i[mm] = Mnew;

            float rsum = 0.0f;
            #pragma unroll
            for (int nn = 0; nn < 4; ++nn) {
                float pe = __expf(s[mm][nn] - Mnew);
                Ps[4 * ty + mm][4 * tx + nn] = pe;
                rsum += pe;
            }
            #pragma unroll
            for (int off = 8; off; off >>= 1)
                rsum += __shfl_xor(rsum, off, 16);
            l_i[mm] = l_i[mm] * alpha + rsum;
            #pragma unroll
            for (int dd = 0; dd < 5; ++dd) o[mm][dd] *= alpha;
        }
        __syncthreads();

        // ---- O += P V  (4 rows x 5 cols per thread, cols tx+16*dd) ----
        #pragma unroll 4
        for (int kj = 0; kj < BK; ++kj) {
            float pv[4], vv[5];
            #pragma unroll
            for (int mm = 0; mm < 4; ++mm) pv[mm] = Ps[4 * ty + mm][kj];
            #pragma unroll
            for (int dd = 0; dd < 5; ++dd) vv[dd] = Vs[kj][tx + 16 * dd];
            #pragma unroll
            for (int mm = 0; mm < 4; ++mm)
                #pragma unroll
                for (int dd = 0; dd < 5; ++dd)
                    o[mm][dd] = fmaf(pv[mm], vv[dd], o[mm][dd]);
        }
    }

    // ---- epilogue: normalize and write into dead Q columns ----
    #pragma unroll
    for (int mm = 0; mm < 4; ++mm) {
        float inv = 1.0f / l_i[mm];
        #pragma unroll
        for (int dd = 0; dd < 5; ++dd) {
            qkv[(size_t)(i0 + 4 * ty + mm) * 960 + h * HDIM + tx + 16 * dd] = o[mm][dd] * inv;
        }
    }
}

// ---------------------------------------------------------------------------
extern "C" void kernel_launch(void* const* d_in, const int* in_sizes, int n_in,
                              void* d_out, int out_size, void* d_ws, size_t ws_size,
                              hipStream_t stream)
{
    const float* x    = (const float*)d_in[0];
    const float* cosb = (const float*)d_in[1];
    const float* sinb = (const float*)d_in[2];
    const float* Wq   = (const float*)d_in[3];
    const float* Wk   = (const float*)d_in[4];
    const float* Wv   = (const float*)d_in[5];
    const float* Wo   = (const float*)d_in[6];
    const float* qw   = (const float*)d_in[7];
    const float* kw   = (const float*)d_in[8];
    float* out = (float*)d_out;

    float* ws   = (float*)d_ws;
    float* qkv  = ws;                                  // [SEQ][960]
    float* qrot = qkv  + (size_t)SEQ * 960;            // [SEQ][640]
    float* krot = qrot + (size_t)SEQ * (NH * HDIM);    // [SEQ][160]

    dim3 blk(256);

    gemm_f32<<<dim3(HIDDEN / 64, SEQ / 64), blk, 0, stream>>>(
        x, Wq, qkv, SEQ, HIDDEN, HIDDEN, HIDDEN, 960);
    gemm_f32<<<dim3((NKV * HDIM + 63) / 64, SEQ / 64), blk, 0, stream>>>(
        x, Wk, qkv + HIDDEN, SEQ, NKV * HDIM, HIDDEN, HIDDEN, 960);
    gemm_f32<<<dim3((NKV * HDIM + 63) / 64, SEQ / 64), blk, 0, stream>>>(
        x, Wv, qkv + HIDDEN + NKV * HDIM, SEQ, NKV * HDIM, HIDDEN, HIDDEN, 960);

    norm_rope_kernel<<<dim3(SEQ, NH + NKV), dim3(128), 0, stream>>>(
        qkv, cosb, sinb, qw, kw, qrot, krot);

    flash_attn<<<dim3(SEQ / BQ, NH), blk, 0, stream>>>(qrot, krot, qkv);

    gemm_f32<<<dim3(HIDDEN / 64, SEQ / 64), blk, 0, stream>>>(
        qkv, Wo, out, SEQ, HIDDEN, HIDDEN, 960, HIDDEN);
}

// Round 3
// 227.437 us; speedup vs baseline: 13.9340x; 2.1143x over previous
//
#include <hip/hip_runtime.h>
#include <hip/hip_bf16.h>
#include <stdint.h>

#define SEQ     4096
#define HIDDEN  640
#define HDIM    80
#define NH      8
#define NKV     2
#define NREP    4
#define WINDOW  512
#define SINK    4
#define BQ      64
#define BK      64

typedef __bf16 bf16x8 __attribute__((ext_vector_type(8)));
typedef float  f32x4  __attribute__((ext_vector_type(4)));

__device__ inline __bf16 f2bf(float f) {
    union { float f; uint32_t u; } x; x.f = f;
    uint32_t r = x.u + 0x7FFF + ((x.u >> 16) & 1);   // RNE, no NaN inputs
    union { unsigned short s; __bf16 b; } y; y.s = (unsigned short)(r >> 16);
    return y.b;
}

// ---------------------------------------------------------------------------
// fp32 -> bf16 elementwise (n multiple of 4)
// ---------------------------------------------------------------------------
__global__ __launch_bounds__(256) void convert_bf16(
    const float* __restrict__ src, __bf16* __restrict__ dst, int n4)
{
    int i = blockIdx.x * 256 + threadIdx.x;
    if (i >= n4) return;
    const float4 v = *(const float4*)&src[4 * i];
    dst[4 * i + 0] = f2bf(v.x);
    dst[4 * i + 1] = f2bf(v.y);
    dst[4 * i + 2] = f2bf(v.z);
    dst[4 * i + 3] = f2bf(v.w);
}

// ---------------------------------------------------------------------------
// Transpose + convert: dst[n][k] = (bf16) src[k][n].  src [K][N], dst ld = K.
// grid (N/32, K/32), block (32,8).
// ---------------------------------------------------------------------------
__global__ __launch_bounds__(256) void transpose_convert(
    const float* __restrict__ src, __bf16* __restrict__ dst,
    int K, int N, int dst_ld)
{
    __shared__ float t[32][33];
    const int n0 = blockIdx.x * 32, k0 = blockIdx.y * 32;
    #pragma unroll
    for (int i = 0; i < 4; ++i) {
        int r = threadIdx.y + 8 * i;
        t[r][threadIdx.x] = src[(size_t)(k0 + r) * N + n0 + threadIdx.x];
    }
    __syncthreads();
    #pragma unroll
    for (int i = 0; i < 4; ++i) {
        int r = threadIdx.y + 8 * i;
        dst[(size_t)(n0 + r) * dst_ld + k0 + threadIdx.x] = f2bf(t[threadIdx.x][r]);
    }
}

// ---------------------------------------------------------------------------
// MFMA bf16 GEMM: C[M,N] = A[M,K] @ B[K,N], fp32 out.
// A [M][K] bf16 row-major (lda=K). BT [>=N][K] bf16 row-major (B transposed).
// 256 threads = 4 waves (2x2), tile 128x128, BK=32, 16x16x32 MFMA.
// M % 128 == 0, K % 32 == 0. Columns >= N are skipped on write (BT rows up
// to the 128-aligned bound must be readable).
// ---------------------------------------------------------------------------
__global__ __launch_bounds__(256) void gemm_bf16_mfma(
    const __bf16* __restrict__ A, const __bf16* __restrict__ BT,
    float* __restrict__ C, int M, int N, int K, int ldc)
{
    __shared__ __bf16 As[128][40];   // row stride 80 B (=16B*5): aligned, 2-way banks
    __shared__ __bf16 Bs[128][40];

    const int tid  = threadIdx.x;
    const int wave = tid >> 6;
    const int lane = tid & 63;
    const int wr = wave >> 1, wc = wave & 1;
    const int m0 = blockIdx.y * 128, n0 = blockIdx.x * 128;

    f32x4 acc[4][4];
    #pragma unroll
    for (int m = 0; m < 4; ++m)
        #pragma unroll
        for (int n = 0; n < 4; ++n) acc[m][n] = (f32x4)0.0f;

    const int srow = tid >> 1;          // 0..127
    const int shalf = tid & 1;          // 16-bf16 half of the 32-wide k row

    for (int k0 = 0; k0 < K; k0 += 32) {
        __syncthreads();
        {
            const size_t ga = (size_t)(m0 + srow) * K + k0 + 16 * shalf;
            bf16x8 a0 = *(const bf16x8*)&A[ga];
            bf16x8 a1 = *(const bf16x8*)&A[ga + 8];
            *(bf16x8*)&As[srow][16 * shalf]     = a0;
            *(bf16x8*)&As[srow][16 * shalf + 8] = a1;
            const size_t gb = (size_t)(n0 + srow) * K + k0 + 16 * shalf;
            bf16x8 b0 = *(const bf16x8*)&BT[gb];
            bf16x8 b1 = *(const bf16x8*)&BT[gb + 8];
            *(bf16x8*)&Bs[srow][16 * shalf]     = b0;
            *(bf16x8*)&Bs[srow][16 * shalf + 8] = b1;
        }
        __syncthreads();

        bf16x8 af[4], bfr[4];
        #pragma unroll
        for (int m = 0; m < 4; ++m)
            af[m] = *(const bf16x8*)&As[wr * 64 + m * 16 + (lane & 15)][8 * (lane >> 4)];
        #pragma unroll
        for (int n = 0; n < 4; ++n)
            bfr[n] = *(const bf16x8*)&Bs[wc * 64 + n * 16 + (lane & 15)][8 * (lane >> 4)];

        #pragma unroll
        for (int m = 0; m < 4; ++m)
            #pragma unroll
            for (int n = 0; n < 4; ++n)
                acc[m][n] = __builtin_amdgcn_mfma_f32_16x16x32_bf16(af[m], bfr[n], acc[m][n], 0, 0, 0);
    }

    // C/D layout: col = lane&15, row = (lane>>4)*4 + r   [m89/m91]
    #pragma unroll
    for (int m = 0; m < 4; ++m) {
        #pragma unroll
        for (int n = 0; n < 4; ++n) {
            const int col = n0 + wc * 64 + n * 16 + (lane & 15);
            if (col < N) {
                const int rbase = m0 + wr * 64 + m * 16 + (lane >> 4) * 4;
                #pragma unroll
                for (int r = 0; r < 4; ++r)
                    C[(size_t)(rbase + r) * ldc + col] = acc[m][n][r];
            }
        }
    }
}

// ---------------------------------------------------------------------------
// RMSNorm + RoPE, IN PLACE on the qkv panel (q cols 0..639, k cols 640..799).
// ---------------------------------------------------------------------------
__global__ __launch_bounds__(128) void norm_rope_kernel(
    float* __restrict__ qkv, const float* __restrict__ cosb,
    const float* __restrict__ sinb, const float* __restrict__ qw,
    const float* __restrict__ kw)
{
    const int row = blockIdx.x;
    const int hh  = blockIdx.y;          // 0..9
    const int tid = threadIdx.x;

    __shared__ float buf[HDIM];
    __shared__ float red[2];

    float* p;
    const float* w;
    if (hh < NH) { p = qkv + (size_t)row * 960 + hh * HDIM;          w = qw; }
    else         { p = qkv + (size_t)row * 960 + HIDDEN + (hh - NH) * HDIM; w = kw; }

    float v = (tid < HDIM) ? p[tid] : 0.0f;
    float sq = v * v;
    #pragma unroll
    for (int off = 32; off; off >>= 1) sq += __shfl_down(sq, off);
    if ((tid & 63) == 0) red[tid >> 6] = sq;
    __syncthreads();
    float rms = rsqrtf((red[0] + red[1]) * (1.0f / HDIM) + 1e-5f);
    if (tid < HDIM) buf[tid] = v * rms * w[tid];
    __syncthreads();

    if (tid < HDIM / 2) {
        float c  = cosb[(size_t)row * (HDIM / 2) + tid];
        float s  = sinb[(size_t)row * (HDIM / 2) + tid];
        float ve = buf[2 * tid];
        float vo = buf[2 * tid + 1];
        p[2 * tid]     = ve * c - vo * s;
        p[2 * tid + 1] = vo * c + ve * s;
    }
}

// ---------------------------------------------------------------------------
// Flash-style windowed attention with sinks (fp32 math), bf16 output.
// Reads roped q (cols 0..639), roped k (640..799), v (800..959) from qkv.
// ---------------------------------------------------------------------------
__global__ __launch_bounds__(256) void flash_attn(
    const float* __restrict__ qkv, __bf16* __restrict__ attnb)
{
    const int i0  = blockIdx.x * BQ;
    const int h   = blockIdx.y;
    const int kvh = h >> 2;
    const int tid = threadIdx.x;
    const int tx  = tid & 15;
    const int ty  = tid >> 4;

    __shared__ float Qs[HDIM][BQ + 1];
    __shared__ float Ks[HDIM][BK + 1];
    __shared__ float Vs[BK][HDIM + 4];
    __shared__ float Ps[BQ][BK + 1];

    const float scale = 0.11180339887498948f;  // 1/sqrt(80)

    #pragma unroll
    for (int p = 0; p < 5; ++p) {
        int idx = tid + 256 * p;
        int qi  = idx / 20;
        int c4  = idx % 20;
        const float4 v = *(const float4*)&qkv[(size_t)(i0 + qi) * 960 + h * HDIM + 4 * c4];
        Qs[4 * c4 + 0][qi] = v.x * scale;
        Qs[4 * c4 + 1][qi] = v.y * scale;
        Qs[4 * c4 + 2][qi] = v.z * scale;
        Qs[4 * c4 + 3][qi] = v.w * scale;
    }

    float m_i[4], l_i[4], o[4][5];
    #pragma unroll
    for (int mm = 0; mm < 4; ++mm) {
        m_i[mm] = -1e30f;
        l_i[mm] = 0.0f;
        #pragma unroll
        for (int dd = 0; dd < 5; ++dd) o[mm][dd] = 0.0f;
    }

    const int w_lo   = i0 - (WINDOW - 1);
    const int w_tile = (w_lo <= 0) ? 0 : (w_lo & ~(BK - 1));
    const int n_win  = (i0 - w_tile) / BK + 1;
    const int n_tiles = n_win + ((w_tile > 0) ? 1 : 0);

    for (int t = 0; t < n_tiles; ++t) {
        const int j0 = (t < n_win) ? (w_tile + t * BK) : 0;

        __syncthreads();

        #pragma unroll
        for (int p = 0; p < 5; ++p) {
            int idx = tid + 256 * p;
            int kj  = idx / 20;
            int c4  = idx % 20;
            const float4 kv4 = *(const float4*)&qkv[(size_t)(j0 + kj) * 960 + HIDDEN + kvh * HDIM + 4 * c4];
            Ks[4 * c4 + 0][kj] = kv4.x;
            Ks[4 * c4 + 1][kj] = kv4.y;
            Ks[4 * c4 + 2][kj] = kv4.z;
            Ks[4 * c4 + 3][kj] = kv4.w;
            const float4 vv4 = *(const float4*)&qkv[(size_t)(j0 + kj) * 960 + 800 + kvh * HDIM + 4 * c4];
            *(float4*)&Vs[kj][4 * c4] = vv4;
        }
        __syncthreads();

        float s[4][4] = {};
        #pragma unroll 2
        for (int d = 0; d < HDIM; ++d) {
            float a[4], b[4];
            #pragma unroll
            for (int mm = 0; mm < 4; ++mm) a[mm] = Qs[d][4 * ty + mm];
            #pragma unroll
            for (int nn = 0; nn < 4; ++nn) b[nn] = Ks[d][4 * tx + nn];
            #pragma unroll
            for (int mm = 0; mm < 4; ++mm)
                #pragma unroll
                for (int nn = 0; nn < 4; ++nn)
                    s[mm][nn] = fmaf(a[mm], b[nn], s[mm][nn]);
        }

        const bool full = (j0 >= i0 - 448) && (j0 <= i0 - 64);
        if (!full) {
            #pragma unroll
            for (int mm = 0; mm < 4; ++mm) {
                int i = i0 + 4 * ty + mm;
                #pragma unroll
                for (int nn = 0; nn < 4; ++nn) {
                    int j = j0 + 4 * tx + nn;
                    bool allowed = (j <= i) && ((j >= i - (WINDOW - 1)) || (j < SINK));
                    if (!allowed) s[mm][nn] = -1e30f;
                }
            }
        }

        #pragma unroll
        for (int mm = 0; mm < 4; ++mm) {
            float rmax = fmaxf(fmaxf(s[mm][0], s[mm][1]), fmaxf(s[mm][2], s[mm][3]));
            #pragma unroll
            for (int off = 8; off; off >>= 1)
                rmax = fmaxf(rmax, __shfl_xor(rmax, off, 16));
            float Mnew  = fmaxf(m_i[mm], rmax);
            float alpha = __expf(m_i[mm] - Mnew);
            m_i[mm] = Mnew;

            float rsum = 0.0f;
            #pragma unroll
            for (int nn = 0; nn < 4; ++nn) {
                float pe = __expf(s[mm][nn] - Mnew);
                Ps[4 * ty + mm][4 * tx + nn] = pe;
                rsum += pe;
            }
            #pragma unroll
            for (int off = 8; off; off >>= 1)
                rsum += __shfl_xor(rsum, off, 16);
            l_i[mm] = l_i[mm] * alpha + rsum;
            #pragma unroll
            for (int dd = 0; dd < 5; ++dd) o[mm][dd] *= alpha;
        }
        __syncthreads();

        #pragma unroll 4
        for (int kj = 0; kj < BK; ++kj) {
            float pv[4], vv[5];
            #pragma unroll
            for (int mm = 0; mm < 4; ++mm) pv[mm] = Ps[4 * ty + mm][kj];
            #pragma unroll
            for (int dd = 0; dd < 5; ++dd) vv[dd] = Vs[kj][tx + 16 * dd];
            #pragma unroll
            for (int mm = 0; mm < 4; ++mm)
                #pragma unroll
                for (int dd = 0; dd < 5; ++dd)
                    o[mm][dd] = fmaf(pv[mm], vv[dd], o[mm][dd]);
        }
    }

    #pragma unroll
    for (int mm = 0; mm < 4; ++mm) {
        float inv = 1.0f / l_i[mm];
        #pragma unroll
        for (int dd = 0; dd < 5; ++dd) {
            attnb[(size_t)(i0 + 4 * ty + mm) * HIDDEN + h * HDIM + tx + 16 * dd] =
                f2bf(o[mm][dd] * inv);
        }
    }
}

// ---------------------------------------------------------------------------
extern "C" void kernel_launch(void* const* d_in, const int* in_sizes, int n_in,
                              void* d_out, int out_size, void* d_ws, size_t ws_size,
                              hipStream_t stream)
{
    const float* x    = (const float*)d_in[0];
    const float* cosb = (const float*)d_in[1];
    const float* sinb = (const float*)d_in[2];
    const float* Wq   = (const float*)d_in[3];
    const float* Wk   = (const float*)d_in[4];
    const float* Wv   = (const float*)d_in[5];
    const float* Wo   = (const float*)d_in[6];
    const float* qw   = (const float*)d_in[7];
    const float* kw   = (const float*)d_in[8];
    float* out = (float*)d_out;

    char* ws = (char*)d_ws;
    float*  qkv    = (float*)ws;                                   // [4096][960] f32
    __bf16* xb     = (__bf16*)(ws + (size_t)SEQ * 960 * 4);        // [4096][640] bf16 (later attnb)
    __bf16* WqkvT  = (__bf16*)(ws + (size_t)SEQ * 960 * 4
                                  + (size_t)SEQ * HIDDEN * 2);     // [1024][640] bf16 (960 used)
    __bf16* WoT    = WqkvT + (size_t)1024 * HIDDEN;                // [640][640] bf16
    // total ws: 15.73 + 5.24 + 1.31 + 0.82 = 23.1 MB

    // ---- converts ----
    convert_bf16<<<dim3(SEQ * HIDDEN / 4 / 256), dim3(256), 0, stream>>>(
        x, xb, SEQ * HIDDEN / 4);
    transpose_convert<<<dim3(HIDDEN / 32, HIDDEN / 32), dim3(32, 8), 0, stream>>>(
        Wq, WqkvT, HIDDEN, HIDDEN, HIDDEN);
    transpose_convert<<<dim3(160 / 32, HIDDEN / 32), dim3(32, 8), 0, stream>>>(
        Wk, WqkvT + (size_t)HIDDEN * HIDDEN, HIDDEN, 160, HIDDEN);
    transpose_convert<<<dim3(160 / 32, HIDDEN / 32), dim3(32, 8), 0, stream>>>(
        Wv, WqkvT + (size_t)800 * HIDDEN, HIDDEN, 160, HIDDEN);
    transpose_convert<<<dim3(HIDDEN / 32, HIDDEN / 32), dim3(32, 8), 0, stream>>>(
        Wo, WoT, HIDDEN, HIDDEN, HIDDEN);

    // ---- QKV projection: xb @ [Wq|Wk|Wv] -> qkv panel ----
    gemm_bf16_mfma<<<dim3(8, SEQ / 128), dim3(256), 0, stream>>>(
        xb, WqkvT, qkv, SEQ, 960, HIDDEN, 960);

    // ---- RMSNorm + RoPE in place ----
    norm_rope_kernel<<<dim3(SEQ, NH + NKV), dim3(128), 0, stream>>>(
        qkv, cosb, sinb, qw, kw);

    // ---- attention (fp32), bf16 out into xb's region ----
    flash_attn<<<dim3(SEQ / BQ, NH), dim3(256), 0, stream>>>(qkv, xb);

    // ---- out projection: attnb @ Wo -> out ----
    gemm_bf16_mfma<<<dim3(HIDDEN / 128, SEQ / 128), dim3(256), 0, stream>>>(
        xb, WoT, out, SEQ, HIDDEN, HIDDEN, HIDDEN);
}

// Round 4
// 118.643 us; speedup vs baseline: 26.7112x; 1.9170x over previous
//
#include <hip/hip_runtime.h>
#include <hip/hip_bf16.h>
#include <stdint.h>

#define SEQ     4096
#define HIDDEN  640
#define HDIM    80
#define NH      8
#define NKV     2
#define WINDOW  512
#define SINK    4
#define BQ      64
#define BK      64
#define KSTR    104   // Ks row stride (bf16): 2-way banks on b128 reads
#define VSTR    72    // Vt/Pl row stride (bf16): 2-way banks

typedef __bf16 bf16x8 __attribute__((ext_vector_type(8)));
typedef float  f32x4  __attribute__((ext_vector_type(4)));

__device__ inline __bf16 f2bf(float f) {
    union { float f; uint32_t u; } x; x.f = f;
    uint32_t r = x.u + 0x7FFF + ((x.u >> 16) & 1);   // RNE, no NaN inputs
    union { unsigned short s; __bf16 b; } y; y.s = (unsigned short)(r >> 16);
    return y.b;
}
__device__ inline float bf2f(unsigned short u) {
    union { uint32_t u; float f; } c; c.u = ((uint32_t)u) << 16; return c.f;
}

// ---------------------------------------------------------------------------
// fp32 -> bf16 elementwise
// ---------------------------------------------------------------------------
__global__ __launch_bounds__(256) void convert_bf16(
    const float* __restrict__ src, __bf16* __restrict__ dst, int n4)
{
    int i = blockIdx.x * 256 + threadIdx.x;
    if (i >= n4) return;
    const float4 v = *(const float4*)&src[4 * i];
    dst[4 * i + 0] = f2bf(v.x);
    dst[4 * i + 1] = f2bf(v.y);
    dst[4 * i + 2] = f2bf(v.z);
    dst[4 * i + 3] = f2bf(v.w);
}

// ---------------------------------------------------------------------------
// Weight transpose + convert: dst[n][k] = (bf16) src[k][n].
// ---------------------------------------------------------------------------
__global__ __launch_bounds__(256) void transpose_convert(
    const float* __restrict__ src, __bf16* __restrict__ dst,
    int K, int N, int dst_ld)
{
    __shared__ float t[32][33];
    const int n0 = blockIdx.x * 32, k0 = blockIdx.y * 32;
    const int tx = threadIdx.x, ty = threadIdx.y;
    #pragma unroll
    for (int i = 0; i < 4; ++i) {
        int r = ty + 8 * i;
        t[r][tx] = src[(size_t)(k0 + r) * N + n0 + tx];
    }
    __syncthreads();
    #pragma unroll
    for (int i = 0; i < 4; ++i) {
        int r = ty + 8 * i;
        dst[(size_t)(n0 + r) * dst_ld + k0 + tx] = f2bf(t[tx][r]);
    }
}

// ---------------------------------------------------------------------------
// MFMA bf16 GEMM: C[M,N] = A[M,K] @ BT^T, OutT output (f32 or bf16).
// ---------------------------------------------------------------------------
template <typename OutT>
__global__ __launch_bounds__(256) void gemm_bf16_mfma(
    const __bf16* __restrict__ A, const __bf16* __restrict__ BT,
    OutT* __restrict__ C, int M, int N, int K, int ldc)
{
    __shared__ __bf16 As[128][40];
    __shared__ __bf16 Bs[128][40];

    const int tid  = threadIdx.x;
    const int wave = tid >> 6;
    const int lane = tid & 63;
    const int wr = wave >> 1, wc = wave & 1;
    const int m0 = blockIdx.y * 128, n0 = blockIdx.x * 128;

    f32x4 acc[4][4];
    #pragma unroll
    for (int m = 0; m < 4; ++m)
        #pragma unroll
        for (int n = 0; n < 4; ++n) acc[m][n] = (f32x4)0.0f;

    const int srow = tid >> 1;
    const int shalf = tid & 1;

    for (int k0 = 0; k0 < K; k0 += 32) {
        __syncthreads();
        {
            const size_t ga = (size_t)(m0 + srow) * K + k0 + 16 * shalf;
            bf16x8 a0 = *(const bf16x8*)&A[ga];
            bf16x8 a1 = *(const bf16x8*)&A[ga + 8];
            *(bf16x8*)&As[srow][16 * shalf]     = a0;
            *(bf16x8*)&As[srow][16 * shalf + 8] = a1;
            const size_t gb = (size_t)(n0 + srow) * K + k0 + 16 * shalf;
            bf16x8 b0 = *(const bf16x8*)&BT[gb];
            bf16x8 b1 = *(const bf16x8*)&BT[gb + 8];
            *(bf16x8*)&Bs[srow][16 * shalf]     = b0;
            *(bf16x8*)&Bs[srow][16 * shalf + 8] = b1;
        }
        __syncthreads();

        bf16x8 af[4], bfr[4];
        #pragma unroll
        for (int m = 0; m < 4; ++m)
            af[m] = *(const bf16x8*)&As[wr * 64 + m * 16 + (lane & 15)][8 * (lane >> 4)];
        #pragma unroll
        for (int n = 0; n < 4; ++n)
            bfr[n] = *(const bf16x8*)&Bs[wc * 64 + n * 16 + (lane & 15)][8 * (lane >> 4)];

        #pragma unroll
        for (int m = 0; m < 4; ++m)
            #pragma unroll
            for (int n = 0; n < 4; ++n)
                acc[m][n] = __builtin_amdgcn_mfma_f32_16x16x32_bf16(af[m], bfr[n], acc[m][n], 0, 0, 0);
    }

    #pragma unroll
    for (int m = 0; m < 4; ++m) {
        #pragma unroll
        for (int n = 0; n < 4; ++n) {
            const int col = n0 + wc * 64 + n * 16 + (lane & 15);
            if (col < N) {
                const int rbase = m0 + wr * 64 + m * 16 + (lane >> 4) * 4;
                #pragma unroll
                for (int r = 0; r < 4; ++r) {
                    if constexpr (sizeof(OutT) == 2)
                        C[(size_t)(rbase + r) * ldc + col] = f2bf(acc[m][n][r]);
                    else
                        C[(size_t)(rbase + r) * ldc + col] = acc[m][n][r];
                }
            }
        }
    }
}

// ---------------------------------------------------------------------------
// RMSNorm + RoPE from bf16 panel. Q heads (hh<8) -> qb (pre-scaled 1/sqrt(80)),
// K heads (hh 8..9) -> kb.
// ---------------------------------------------------------------------------
__global__ __launch_bounds__(128) void norm_rope_kernel(
    const unsigned short* __restrict__ qkvb, const float* __restrict__ cosb,
    const float* __restrict__ sinb, const float* __restrict__ qw,
    const float* __restrict__ kw, __bf16* __restrict__ qb,
    __bf16* __restrict__ kb)
{
    const int row = blockIdx.x;
    const int hh  = blockIdx.y;          // 0..9
    const int tid = threadIdx.x;

    __shared__ float buf[HDIM];
    __shared__ float red[2];

    const unsigned short* p;
    const float* w;
    __bf16* dst;
    float outscale;
    if (hh < NH) {
        p = qkvb + (size_t)row * 960 + hh * HDIM;
        w = qw; dst = qb + (size_t)row * HIDDEN + hh * HDIM;
        outscale = 0.11180339887498948f;
    } else {
        p = qkvb + (size_t)row * 960 + HIDDEN + (hh - NH) * HDIM;
        w = kw; dst = kb + (size_t)row * (NKV * HDIM) + (hh - NH) * HDIM;
        outscale = 1.0f;
    }

    float v = (tid < HDIM) ? bf2f(p[tid]) : 0.0f;
    float sq = v * v;
    #pragma unroll
    for (int off = 32; off; off >>= 1) sq += __shfl_down(sq, off);
    if ((tid & 63) == 0) red[tid >> 6] = sq;
    __syncthreads();
    float rms = rsqrtf((red[0] + red[1]) * (1.0f / HDIM) + 1e-5f);
    if (tid < HDIM) buf[tid] = v * rms * w[tid];
    __syncthreads();

    if (tid < HDIM / 2) {
        float c  = cosb[(size_t)row * (HDIM / 2) + tid];
        float s  = sinb[(size_t)row * (HDIM / 2) + tid];
        float ve = buf[2 * tid];
        float vo = buf[2 * tid + 1];
        dst[2 * tid]     = f2bf((ve * c - vo * s) * outscale);
        dst[2 * tid + 1] = f2bf((vo * c + ve * s) * outscale);
    }
}

// ---------------------------------------------------------------------------
// V transpose: vtb[kvh][d][seq] = panel v cols (bf16 bit copy).
// grid (SEQ/32, 160/32), block (32,8).
// ---------------------------------------------------------------------------
__global__ __launch_bounds__(256) void v_transpose(
    const unsigned short* __restrict__ qkvb, unsigned short* __restrict__ vtb)
{
    __shared__ unsigned short t[32][33];
    const int s0 = blockIdx.x * 32;
    const int c0 = blockIdx.y * 32;
    const int tx = threadIdx.x, ty = threadIdx.y;
    #pragma unroll
    for (int i = 0; i < 4; ++i)
        t[ty + 8 * i][tx] = qkvb[(size_t)(s0 + ty + 8 * i) * 960 + 800 + c0 + tx];
    __syncthreads();
    #pragma unroll
    for (int i = 0; i < 4; ++i) {
        int g = c0 + ty + 8 * i;           // 0..159
        int kvh = g / HDIM, d = g % HDIM;
        vtb[((size_t)kvh * HDIM + d) * SEQ + s0 + tx] = t[tx][ty + 8 * i];
    }
}

// ---------------------------------------------------------------------------
// MFMA flash attention. 4 waves x 16 q-rows, key tiles of 64.
// qb pre-scaled. kb row-major. vtb d-major. Output bf16.
// ---------------------------------------------------------------------------
__global__ __launch_bounds__(256) void flash_attn_mfma(
    const __bf16* __restrict__ qb, const __bf16* __restrict__ kb,
    const __bf16* __restrict__ vtb, __bf16* __restrict__ attnb)
{
    const int i0   = blockIdx.x * BQ;
    const int h    = blockIdx.y;
    const int kvh  = h >> 2;
    const int tid  = threadIdx.x;
    const int w    = tid >> 6;
    const int lane = tid & 63;
    const int l15  = lane & 15;
    const int lq   = lane >> 4;

    __shared__ __bf16 Ks[BK][KSTR];      // 13312 B
    __shared__ __bf16 Vt[HDIM][VSTR];    // 11520 B
    __shared__ __bf16 Pl[BQ][VSTR];      //  9216 B

    // zero K pad columns 80..95 (never rewritten)
    if (tid < 128) {
        int r = tid >> 1, c = HDIM + 8 * (tid & 1);
        *(float4*)&Ks[r][c] = make_float4(0.f, 0.f, 0.f, 0.f);
    }

    // preload Q A-fragments (wave-private rows i0+16w+l15)
    bf16x8 qf[3];
    {
        const __bf16* qrow = qb + (size_t)(i0 + 16 * w + l15) * HIDDEN + h * HDIM;
        #pragma unroll
        for (int ks = 0; ks < 3; ++ks) {
            int off = 32 * ks + 8 * lq;
            if (off >= HDIM) off = 0;     // dummy: multiplied by zeroed K pad
            qf[ks] = *(const bf16x8*)&qrow[off];
        }
    }

    float m_i[4], l_i[4];
    f32x4 o[5];
    #pragma unroll
    for (int r = 0; r < 4; ++r) { m_i[r] = -1e30f; l_i[r] = 0.0f; }
    #pragma unroll
    for (int n = 0; n < 5; ++n) o[n] = (f32x4)0.0f;

    const int w_lo   = i0 - (WINDOW - 1);
    const int w_tile = (w_lo <= 0) ? 0 : (w_lo & ~(BK - 1));
    const int n_win  = (i0 - w_tile) / BK + 1;
    const int n_tiles = n_win + ((w_tile > 0) ? 1 : 0);

    for (int t = 0; t < n_tiles; ++t) {
        const int j0 = (t < n_win) ? (w_tile + t * BK) : 0;

        __syncthreads();   // previous tile's readers done
        // stage K tile (64 x 80)
        for (int idx = tid; idx < 640; idx += 256) {
            int r = idx / 10, c8 = idx % 10;
            *(bf16x8*)&Ks[r][8 * c8] =
                *(const bf16x8*)&kb[(size_t)(j0 + r) * (NKV * HDIM) + kvh * HDIM + 8 * c8];
        }
        // stage V tile transposed (80 x 64)
        const __bf16* vbase = vtb + (size_t)kvh * HDIM * SEQ + j0;
        for (int idx = tid; idx < 640; idx += 256) {
            int d = idx >> 3, c8 = idx & 7;
            *(bf16x8*)&Vt[d][8 * c8] = *(const bf16x8*)&vbase[(size_t)d * SEQ + 8 * c8];
        }
        __syncthreads();

        // ---- S = Q K^T : 12 MFMA ----
        f32x4 sacc[4];
        #pragma unroll
        for (int n = 0; n < 4; ++n) sacc[n] = (f32x4)0.0f;
        #pragma unroll
        for (int ks = 0; ks < 3; ++ks) {
            #pragma unroll
            for (int n = 0; n < 4; ++n) {
                bf16x8 kf = *(const bf16x8*)&Ks[n * 16 + l15][32 * ks + 8 * lq];
                sacc[n] = __builtin_amdgcn_mfma_f32_16x16x32_bf16(qf[ks], kf, sacc[n], 0, 0, 0);
            }
        }

        // ---- mask ----
        const bool full = (j0 >= i0 - 448) && (j0 <= i0 - 64);
        if (!full) {
            #pragma unroll
            for (int n = 0; n < 4; ++n) {
                int j = j0 + 16 * n + l15;
                #pragma unroll
                for (int r = 0; r < 4; ++r) {
                    int i = i0 + 16 * w + 4 * lq + r;
                    bool allowed = (j <= i) && ((j >= i - (WINDOW - 1)) || (j < SINK));
                    if (!allowed) sacc[n][r] = -1e30f;
                }
            }
        }

        // ---- online softmax (per lane: 4 rows) ----
        #pragma unroll
        for (int r = 0; r < 4; ++r) {
            float rmax = fmaxf(fmaxf(sacc[0][r], sacc[1][r]), fmaxf(sacc[2][r], sacc[3][r]));
            rmax = fmaxf(rmax, __shfl_xor(rmax, 1));
            rmax = fmaxf(rmax, __shfl_xor(rmax, 2));
            rmax = fmaxf(rmax, __shfl_xor(rmax, 4));
            rmax = fmaxf(rmax, __shfl_xor(rmax, 8));
            float Mnew  = fmaxf(m_i[r], rmax);
            float alpha = __expf(m_i[r] - Mnew);
            m_i[r] = Mnew;

            float rsum = 0.0f;
            #pragma unroll
            for (int n = 0; n < 4; ++n) {
                float pe = __expf(sacc[n][r] - Mnew);
                Pl[16 * w + 4 * lq + r][16 * n + l15] = f2bf(pe);
                rsum += pe;
            }
            rsum += __shfl_xor(rsum, 1);
            rsum += __shfl_xor(rsum, 2);
            rsum += __shfl_xor(rsum, 4);
            rsum += __shfl_xor(rsum, 8);
            l_i[r] = l_i[r] * alpha + rsum;
            #pragma unroll
            for (int n = 0; n < 5; ++n) o[n][r] *= alpha;
        }

        // ---- O += P V : wave-private P rows, 10 MFMA ----
        #pragma unroll
        for (int ks = 0; ks < 2; ++ks) {
            bf16x8 pf = *(const bf16x8*)&Pl[16 * w + l15][32 * ks + 8 * lq];
            #pragma unroll
            for (int n = 0; n < 5; ++n) {
                bf16x8 vf = *(const bf16x8*)&Vt[16 * n + l15][32 * ks + 8 * lq];
                o[n] = __builtin_amdgcn_mfma_f32_16x16x32_bf16(pf, vf, o[n], 0, 0, 0);
            }
        }
    }

    // ---- epilogue ----
    #pragma unroll
    for (int r = 0; r < 4; ++r) {
        float inv = 1.0f / l_i[r];
        int row = i0 + 16 * w + 4 * lq + r;
        #pragma unroll
        for (int n = 0; n < 5; ++n)
            attnb[(size_t)row * HIDDEN + h * HDIM + 16 * n + l15] = f2bf(o[n][r] * inv);
    }
}

// ---------------------------------------------------------------------------
extern "C" void kernel_launch(void* const* d_in, const int* in_sizes, int n_in,
                              void* d_out, int out_size, void* d_ws, size_t ws_size,
                              hipStream_t stream)
{
    const float* x    = (const float*)d_in[0];
    const float* cosb = (const float*)d_in[1];
    const float* sinb = (const float*)d_in[2];
    const float* Wq   = (const float*)d_in[3];
    const float* Wk   = (const float*)d_in[4];
    const float* Wv   = (const float*)d_in[5];
    const float* Wo   = (const float*)d_in[6];
    const float* qw   = (const float*)d_in[7];
    const float* kw   = (const float*)d_in[8];
    float* out = (float*)d_out;

    char* ws = (char*)d_ws;
    __bf16* qkvb  = (__bf16*)ws;                                 // [4096][960]
    __bf16* xb    = qkvb + (size_t)SEQ * 960;                    // [4096][640] -> attnb
    __bf16* qb    = xb   + (size_t)SEQ * HIDDEN;                 // [4096][640]
    __bf16* kb    = qb   + (size_t)SEQ * HIDDEN;                 // [4096][160]
    __bf16* vtb   = kb   + (size_t)SEQ * 160;                    // [2][80][4096]
    __bf16* WqkvT = vtb  + (size_t)2 * HDIM * SEQ;               // [1024][640]
    __bf16* WoT   = WqkvT + (size_t)1024 * HIDDEN;               // [640][640]
    // total 23.1 MB

    convert_bf16<<<dim3(SEQ * HIDDEN / 4 / 256), dim3(256), 0, stream>>>(
        x, xb, SEQ * HIDDEN / 4);
    transpose_convert<<<dim3(HIDDEN / 32, HIDDEN / 32), dim3(32, 8), 0, stream>>>(
        Wq, WqkvT, HIDDEN, HIDDEN, HIDDEN);
    transpose_convert<<<dim3(160 / 32, HIDDEN / 32), dim3(32, 8), 0, stream>>>(
        Wk, WqkvT + (size_t)HIDDEN * HIDDEN, HIDDEN, 160, HIDDEN);
    transpose_convert<<<dim3(160 / 32, HIDDEN / 32), dim3(32, 8), 0, stream>>>(
        Wv, WqkvT + (size_t)800 * HIDDEN, HIDDEN, 160, HIDDEN);
    transpose_convert<<<dim3(HIDDEN / 32, HIDDEN / 32), dim3(32, 8), 0, stream>>>(
        Wo, WoT, HIDDEN, HIDDEN, HIDDEN);

    // QKV projection -> bf16 panel
    gemm_bf16_mfma<__bf16><<<dim3(8, SEQ / 128), dim3(256), 0, stream>>>(
        xb, WqkvT, qkvb, SEQ, 960, HIDDEN, 960);

    // RMSNorm + RoPE -> qb (scaled), kb
    norm_rope_kernel<<<dim3(SEQ, NH + NKV), dim3(128), 0, stream>>>(
        (const unsigned short*)qkvb, cosb, sinb, qw, kw, qb, kb);

    // V transpose -> vtb
    v_transpose<<<dim3(SEQ / 32, 160 / 32), dim3(32, 8), 0, stream>>>(
        (const unsigned short*)qkvb, (unsigned short*)vtb);

    // MFMA flash attention -> attnb (aliases xb, dead after QKV GEMM)
    flash_attn_mfma<<<dim3(SEQ / BQ, NH), dim3(256), 0, stream>>>(
        qb, kb, vtb, xb);

    // out projection
    gemm_bf16_mfma<float><<<dim3(HIDDEN / 128, SEQ / 128), dim3(256), 0, stream>>>(
        xb, WoT, out, SEQ, HIDDEN, HIDDEN, HIDDEN);
}

// Round 7
// 95.584 us; speedup vs baseline: 33.1552x; 1.2412x over previous
//
#include <hip/hip_runtime.h>
#include <hip/hip_bf16.h>
#include <stdint.h>

#define SEQ     4096
#define HIDDEN  640
#define HDIM    80
#define NH      8
#define NKV     2
#define WINDOW  512
#define SINK    4
#define BQ      64
#define BK      64
#define KSTR    104   // Ks row stride (bf16): 2-way banks on b128 reads
#define VSTR    72    // Vt/Pl row stride (bf16): 2-way banks

typedef __bf16 bf16x8 __attribute__((ext_vector_type(8)));
typedef float  f32x4  __attribute__((ext_vector_type(4)));

__device__ inline __bf16 f2bf(float f) {
    union { float f; uint32_t u; } x; x.f = f;
    uint32_t r = x.u + 0x7FFF + ((x.u >> 16) & 1);   // RNE, no NaN inputs
    union { unsigned short s; __bf16 b; } y; y.s = (unsigned short)(r >> 16);
    return y.b;
}
__device__ inline float bf2f(unsigned short u) {
    union { uint32_t u; float f; } c; c.u = ((uint32_t)u) << 16; return c.f;
}

// ---------------------------------------------------------------------------
// fp32 -> bf16 elementwise
// ---------------------------------------------------------------------------
__global__ __launch_bounds__(256) void convert_bf16(
    const float* __restrict__ src, __bf16* __restrict__ dst, int n4)
{
    int i = blockIdx.x * 256 + threadIdx.x;
    if (i >= n4) return;
    const float4 v = *(const float4*)&src[4 * i];
    dst[4 * i + 0] = f2bf(v.x);
    dst[4 * i + 1] = f2bf(v.y);
    dst[4 * i + 2] = f2bf(v.z);
    dst[4 * i + 3] = f2bf(v.w);
}

// ---------------------------------------------------------------------------
// Weight transpose + convert: dst[n][k] = (bf16) src[k][n].
// ---------------------------------------------------------------------------
__global__ __launch_bounds__(256) void transpose_convert(
    const float* __restrict__ src, __bf16* __restrict__ dst,
    int K, int N, int dst_ld)
{
    __shared__ float t[32][33];
    const int n0 = blockIdx.x * 32, k0 = blockIdx.y * 32;
    const int tx = threadIdx.x, ty = threadIdx.y;
    #pragma unroll
    for (int i = 0; i < 4; ++i) {
        int r = ty + 8 * i;
        t[r][tx] = src[(size_t)(k0 + r) * N + n0 + tx];
    }
    __syncthreads();
    #pragma unroll
    for (int i = 0; i < 4; ++i) {
        int r = ty + 8 * i;
        dst[(size_t)(n0 + r) * dst_ld + k0 + tx] = f2bf(t[tx][r]);
    }
}

// ---------------------------------------------------------------------------
// MFMA bf16 GEMM: C[M,N] = A[M,K] @ BT^T, OutT out. 512 threads = 8 waves
// (2 M x 4 N), tile 128x128, BK=32, double-buffered LDS, 1 barrier/K-step.
// Staging: threads 0..255 stage A, threads 256..511 stage B. Each thread
// stages 16 bf16 (two bf16x8): row sc>>1, cols [16*(sc&1), 16*(sc&1)+16).
// 256 threads x 16 elems = 4096 = 128 rows x 32 k-cols. Prefetch to regs,
// write-late into the alternate buffer.
// ---------------------------------------------------------------------------
template <typename OutT>
__global__ __launch_bounds__(512) void gemm_bf16_mfma(
    const __bf16* __restrict__ A, const __bf16* __restrict__ BT,
    OutT* __restrict__ C, int M, int N, int K, int ldc)
{
    __shared__ __bf16 As[2][128][40];   // 20480 B
    __shared__ __bf16 Bs[2][128][40];   // 20480 B
    const int BUFE = 128 * 40;          // elems per buffer

    const int tid  = threadIdx.x;
    const int wave = tid >> 6;
    const int lane = tid & 63;
    const int wr = wave >> 2, wc = wave & 3;     // 2 x 4 wave grid
    const int l15 = lane & 15, lq = lane >> 4;
    const int m0 = blockIdx.y * 128, n0 = blockIdx.x * 128;

    f32x4 acc[4][2];
    #pragma unroll
    for (int m = 0; m < 4; ++m)
        #pragma unroll
        for (int n = 0; n < 2; ++n) acc[m][n] = (f32x4)0.0f;

    // staging role: 16 bf16 per thread
    const int sArr  = tid >> 8;          // 0: A, 1: B
    const int sc    = tid & 255;
    const int srow  = sc >> 1;           // 0..127
    const int shalf = sc & 1;            // 16-col half
    const __bf16* gsrc = sArr ? BT : A;
    const int     grow = sArr ? n0 : m0;
    const size_t  g0   = (size_t)(grow + srow) * K + 16 * shalf;
    __bf16* ldst = (sArr ? &Bs[0][0][0] : &As[0][0][0]) + srow * 40 + 16 * shalf;

    // prologue: stage k-step 0 into buffer 0
    bf16x8 rg0 = *(const bf16x8*)&gsrc[g0];
    bf16x8 rg1 = *(const bf16x8*)&gsrc[g0 + 8];
    *(bf16x8*)ldst       = rg0;
    *(bf16x8*)(ldst + 8) = rg1;
    __syncthreads();

    const int nk = K >> 5;
    for (int ks = 0; ks < nk; ++ks) {
        const int cur = ks & 1;
        if (ks + 1 < nk) {                        // prefetch next step
            rg0 = *(const bf16x8*)&gsrc[g0 + (size_t)(ks + 1) * 32];
            rg1 = *(const bf16x8*)&gsrc[g0 + (size_t)(ks + 1) * 32 + 8];
        }

        bf16x8 af[4], bfr[2];
        #pragma unroll
        for (int m = 0; m < 4; ++m)
            af[m] = *(const bf16x8*)&As[cur][wr * 64 + m * 16 + l15][8 * lq];
        #pragma unroll
        for (int n = 0; n < 2; ++n)
            bfr[n] = *(const bf16x8*)&Bs[cur][wc * 32 + n * 16 + l15][8 * lq];

        __builtin_amdgcn_s_setprio(1);
        #pragma unroll
        for (int m = 0; m < 4; ++m)
            #pragma unroll
            for (int n = 0; n < 2; ++n)
                acc[m][n] = __builtin_amdgcn_mfma_f32_16x16x32_bf16(af[m], bfr[n], acc[m][n], 0, 0, 0);
        __builtin_amdgcn_s_setprio(0);

        if (ks + 1 < nk) {                        // write-late into other buffer
            *(bf16x8*)(ldst + (cur ^ 1) * BUFE)     = rg0;
            *(bf16x8*)(ldst + (cur ^ 1) * BUFE + 8) = rg1;
        }
        __syncthreads();
    }

    #pragma unroll
    for (int m = 0; m < 4; ++m) {
        #pragma unroll
        for (int n = 0; n < 2; ++n) {
            const int col = n0 + wc * 32 + n * 16 + l15;
            if (col < N) {
                const int rbase = m0 + wr * 64 + m * 16 + 4 * lq;
                #pragma unroll
                for (int r = 0; r < 4; ++r) {
                    if constexpr (sizeof(OutT) == 2)
                        C[(size_t)(rbase + r) * ldc + col] = f2bf(acc[m][n][r]);
                    else
                        C[(size_t)(rbase + r) * ldc + col] = acc[m][n][r];
                }
            }
        }
    }
}

// ---------------------------------------------------------------------------
// RMSNorm + RoPE from bf16 panel. Q heads -> qb (pre-scaled), K heads -> kb.
// ---------------------------------------------------------------------------
__global__ __launch_bounds__(128) void norm_rope_kernel(
    const unsigned short* __restrict__ qkvb, const float* __restrict__ cosb,
    const float* __restrict__ sinb, const float* __restrict__ qw,
    const float* __restrict__ kw, __bf16* __restrict__ qb,
    __bf16* __restrict__ kb)
{
    const int row = blockIdx.x;
    const int hh  = blockIdx.y;          // 0..9
    const int tid = threadIdx.x;

    __shared__ float buf[HDIM];
    __shared__ float red[2];

    const unsigned short* p;
    const float* w;
    __bf16* dst;
    float outscale;
    if (hh < NH) {
        p = qkvb + (size_t)row * 960 + hh * HDIM;
        w = qw; dst = qb + (size_t)row * HIDDEN + hh * HDIM;
        outscale = 0.11180339887498948f;
    } else {
        p = qkvb + (size_t)row * 960 + HIDDEN + (hh - NH) * HDIM;
        w = kw; dst = kb + (size_t)row * (NKV * HDIM) + (hh - NH) * HDIM;
        outscale = 1.0f;
    }

    float v = (tid < HDIM) ? bf2f(p[tid]) : 0.0f;
    float sq = v * v;
    #pragma unroll
    for (int off = 32; off; off >>= 1) sq += __shfl_down(sq, off);
    if ((tid & 63) == 0) red[tid >> 6] = sq;
    __syncthreads();
    float rms = rsqrtf((red[0] + red[1]) * (1.0f / HDIM) + 1e-5f);
    if (tid < HDIM) buf[tid] = v * rms * w[tid];
    __syncthreads();

    if (tid < HDIM / 2) {
        float c  = cosb[(size_t)row * (HDIM / 2) + tid];
        float s  = sinb[(size_t)row * (HDIM / 2) + tid];
        float ve = buf[2 * tid];
        float vo = buf[2 * tid + 1];
        dst[2 * tid]     = f2bf((ve * c - vo * s) * outscale);
        dst[2 * tid + 1] = f2bf((vo * c + ve * s) * outscale);
    }
}

// ---------------------------------------------------------------------------
// V transpose: vtb[kvh][d][seq] = panel v cols (bf16 bit copy).
// ---------------------------------------------------------------------------
__global__ __launch_bounds__(256) void v_transpose(
    const unsigned short* __restrict__ qkvb, unsigned short* __restrict__ vtb)
{
    __shared__ unsigned short t[32][33];
    const int s0 = blockIdx.x * 32;
    const int c0 = blockIdx.y * 32;
    const int tx = threadIdx.x, ty = threadIdx.y;
    #pragma unroll
    for (int i = 0; i < 4; ++i)
        t[ty + 8 * i][tx] = qkvb[(size_t)(s0 + ty + 8 * i) * 960 + 800 + c0 + tx];
    __syncthreads();
    #pragma unroll
    for (int i = 0; i < 4; ++i) {
        int g = c0 + ty + 8 * i;           // 0..159
        int kvh = g / HDIM, d = g % HDIM;
        vtb[((size_t)kvh * HDIM + d) * SEQ + s0 + tx] = t[tx][ty + 8 * i];
    }
}

// ---------------------------------------------------------------------------
// MFMA flash attention, double-buffered K/V LDS, 1 barrier per tile.
// 4 waves x 16 q-rows, key tiles of 64. qb pre-scaled, kb row-major,
// vtb d-major. Output bf16.
// ---------------------------------------------------------------------------
__global__ __launch_bounds__(256) void flash_attn_mfma(
    const __bf16* __restrict__ qb, const __bf16* __restrict__ kb,
    const __bf16* __restrict__ vtb, __bf16* __restrict__ attnb)
{
    const int i0   = blockIdx.x * BQ;
    const int h    = blockIdx.y;
    const int kvh  = h >> 2;
    const int tid  = threadIdx.x;
    const int w    = tid >> 6;
    const int lane = tid & 63;
    const int l15  = lane & 15;
    const int lq   = lane >> 4;

    __shared__ __bf16 Ks[2][BK][KSTR];   // 26624 B
    __shared__ __bf16 Vt[2][HDIM][VSTR]; // 23040 B
    __shared__ __bf16 Pl[BQ][VSTR];      //  9216 B  (total 58880 B -> 2 blk/CU)

    // zero K pad columns 80..95 of BOTH buffers (never rewritten)
    {
        int b = tid >> 7, r = (tid >> 1) & 63, c = HDIM + 8 * (tid & 1);
        *(float4*)&Ks[b][r][c] = make_float4(0.f, 0.f, 0.f, 0.f);
    }

    // per-thread staging descriptors (chunk = tid + 256*i, 640 chunks each)
    int koff[3], voff[3];
    bool act[3];
    #pragma unroll
    for (int i = 0; i < 3; ++i) {
        int c = tid + 256 * i;
        act[i] = (c < 640);
        int cc = act[i] ? c : 0;
        koff[i] = (cc / 10) * (NKV * HDIM) + 8 * (cc % 10);   // + kvh*HDIM + j0*320
        voff[i] = (cc >> 3) * SEQ + 8 * (cc & 7);             // + j0
    }
    const __bf16* kbase = kb + kvh * HDIM;
    const __bf16* vbase = vtb + (size_t)kvh * HDIM * SEQ;
    // LDS store targets (fixed per thread)
    __bf16* ksdst[3];
    __bf16* vsdst[3];
    #pragma unroll
    for (int i = 0; i < 3; ++i) {
        int cc = act[i] ? (tid + 256 * i) : 0;
        ksdst[i] = &Ks[0][cc / 10][8 * (cc % 10)];
        vsdst[i] = &Vt[0][cc >> 3][8 * (cc & 7)];
    }
    const size_t ksbuf = (size_t)BK * KSTR;      // elems per Ks buffer
    const size_t vsbuf = (size_t)HDIM * VSTR;

    // preload Q A-fragments (wave-private rows i0+16w+l15)
    bf16x8 qf[3];
    {
        const __bf16* qrow = qb + (size_t)(i0 + 16 * w + l15) * HIDDEN + h * HDIM;
        #pragma unroll
        for (int ks = 0; ks < 3; ++ks) {
            int off = 32 * ks + 8 * lq;
            if (off >= HDIM) off = 0;     // dummy: multiplied by zeroed K pad
            qf[ks] = *(const bf16x8*)&qrow[off];
        }
    }

    float m_i[4], l_i[4];
    f32x4 o[5];
    #pragma unroll
    for (int r = 0; r < 4; ++r) { m_i[r] = -1e30f; l_i[r] = 0.0f; }
    #pragma unroll
    for (int n = 0; n < 5; ++n) o[n] = (f32x4)0.0f;

    const int w_lo   = i0 - (WINDOW - 1);
    const int w_tile = (w_lo <= 0) ? 0 : (w_lo & ~(BK - 1));
    const int n_win  = (i0 - w_tile) / BK + 1;
    const int n_tiles = n_win + ((w_tile > 0) ? 1 : 0);

    // prologue: stage tile 0 into buffer 0
    bf16x8 krg[3], vrg[3];
    {
        const int j0 = w_tile;            // tile 0
        #pragma unroll
        for (int i = 0; i < 3; ++i) {
            if (act[i]) {
                krg[i] = *(const bf16x8*)&kbase[(size_t)j0 * (NKV * HDIM) + koff[i]];
                vrg[i] = *(const bf16x8*)&vbase[(size_t)j0 + voff[i]];
            }
        }
        #pragma unroll
        for (int i = 0; i < 3; ++i) {
            if (act[i]) {
                *(bf16x8*)ksdst[i] = krg[i];
                *(bf16x8*)vsdst[i] = vrg[i];
            }
        }
    }
    __syncthreads();

    for (int t = 0; t < n_tiles; ++t) {
        const int cur = t & 1;
        const int j0 = (t < n_win) ? (w_tile + t * BK) : 0;

        // ---- prefetch next tile into registers ----
        if (t + 1 < n_tiles) {
            const int j1 = (t + 1 < n_win) ? (w_tile + (t + 1) * BK) : 0;
            #pragma unroll
            for (int i = 0; i < 3; ++i) {
                if (act[i]) {
                    krg[i] = *(const bf16x8*)&kbase[(size_t)j1 * (NKV * HDIM) + koff[i]];
                    vrg[i] = *(const bf16x8*)&vbase[(size_t)j1 + voff[i]];
                }
            }
        }

        // ---- S = Q K^T : 12 MFMA ----
        f32x4 sacc[4];
        #pragma unroll
        for (int n = 0; n < 4; ++n) sacc[n] = (f32x4)0.0f;
        __builtin_amdgcn_s_setprio(1);
        #pragma unroll
        for (int ks = 0; ks < 3; ++ks) {
            #pragma unroll
            for (int n = 0; n < 4; ++n) {
                bf16x8 kf = *(const bf16x8*)&Ks[cur][n * 16 + l15][32 * ks + 8 * lq];
                sacc[n] = __builtin_amdgcn_mfma_f32_16x16x32_bf16(qf[ks], kf, sacc[n], 0, 0, 0);
            }
        }
        __builtin_amdgcn_s_setprio(0);

        // ---- mask ----
        const bool full = (j0 >= i0 - 448) && (j0 <= i0 - 64);
        if (!full) {
            #pragma unroll
            for (int n = 0; n < 4; ++n) {
                int j = j0 + 16 * n + l15;
                #pragma unroll
                for (int r = 0; r < 4; ++r) {
                    int i = i0 + 16 * w + 4 * lq + r;
                    bool allowed = (j <= i) && ((j >= i - (WINDOW - 1)) || (j < SINK));
                    if (!allowed) sacc[n][r] = -1e30f;
                }
            }
        }

        // ---- online softmax (per lane: 4 rows) ----
        #pragma unroll
        for (int r = 0; r < 4; ++r) {
            float rmax = fmaxf(fmaxf(sacc[0][r], sacc[1][r]), fmaxf(sacc[2][r], sacc[3][r]));
            rmax = fmaxf(rmax, __shfl_xor(rmax, 1));
            rmax = fmaxf(rmax, __shfl_xor(rmax, 2));
            rmax = fmaxf(rmax, __shfl_xor(rmax, 4));
            rmax = fmaxf(rmax, __shfl_xor(rmax, 8));
            float Mnew  = fmaxf(m_i[r], rmax);
            float alpha = __expf(m_i[r] - Mnew);
            m_i[r] = Mnew;

            float rsum = 0.0f;
            #pragma unroll
            for (int n = 0; n < 4; ++n) {
                float pe = __expf(sacc[n][r] - Mnew);
                Pl[16 * w + 4 * lq + r][16 * n + l15] = f2bf(pe);
                rsum += pe;
            }
            rsum += __shfl_xor(rsum, 1);
            rsum += __shfl_xor(rsum, 2);
            rsum += __shfl_xor(rsum, 4);
            rsum += __shfl_xor(rsum, 8);
            l_i[r] = l_i[r] * alpha + rsum;
            #pragma unroll
            for (int n = 0; n < 5; ++n) o[n][r] *= alpha;
        }

        // ---- O += P V : wave-private P rows, 10 MFMA ----
        __builtin_amdgcn_s_setprio(1);
        #pragma unroll
        for (int ks = 0; ks < 2; ++ks) {
            bf16x8 pf = *(const bf16x8*)&Pl[16 * w + l15][32 * ks + 8 * lq];
            #pragma unroll
            for (int n = 0; n < 5; ++n) {
                bf16x8 vf = *(const bf16x8*)&Vt[cur][16 * n + l15][32 * ks + 8 * lq];
                o[n] = __builtin_amdgcn_mfma_f32_16x16x32_bf16(pf, vf, o[n], 0, 0, 0);
            }
        }
        __builtin_amdgcn_s_setprio(0);

        // ---- write-late: store prefetched tile into the other buffer ----
        if (t + 1 < n_tiles) {
            const size_t bo = (size_t)(cur ^ 1);
            #pragma unroll
            for (int i = 0; i < 3; ++i) {
                if (act[i]) {
                    *(bf16x8*)(ksdst[i] + bo * ksbuf) = krg[i];
                    *(bf16x8*)(vsdst[i] + bo * vsbuf) = vrg[i];
                }
            }
        }
        __syncthreads();
    }

    // ---- epilogue ----
    #pragma unroll
    for (int r = 0; r < 4; ++r) {
        float inv = 1.0f / l_i[r];
        int row = i0 + 16 * w + 4 * lq + r;
        #pragma unroll
        for (int n = 0; n < 5; ++n)
            attnb[(size_t)row * HIDDEN + h * HDIM + 16 * n + l15] = f2bf(o[n][r] * inv);
    }
}

// ---------------------------------------------------------------------------
extern "C" void kernel_launch(void* const* d_in, const int* in_sizes, int n_in,
                              void* d_out, int out_size, void* d_ws, size_t ws_size,
                              hipStream_t stream)
{
    const float* x    = (const float*)d_in[0];
    const float* cosb = (const float*)d_in[1];
    const float* sinb = (const float*)d_in[2];
    const float* Wq   = (const float*)d_in[3];
    const float* Wk   = (const float*)d_in[4];
    const float* Wv   = (const float*)d_in[5];
    const float* Wo   = (const float*)d_in[6];
    const float* qw   = (const float*)d_in[7];
    const float* kw   = (const float*)d_in[8];
    float* out = (float*)d_out;

    char* ws = (char*)d_ws;
    __bf16* qkvb  = (__bf16*)ws;                                 // [4096][960]
    __bf16* xb    = qkvb + (size_t)SEQ * 960;                    // [4096][640] -> attnb
    __bf16* qb    = xb   + (size_t)SEQ * HIDDEN;                 // [4096][640]
    __bf16* kb    = qb   + (size_t)SEQ * HIDDEN;                 // [4096][160]
    __bf16* vtb   = kb   + (size_t)SEQ * 160;                    // [2][80][4096]
    __bf16* WqkvT = vtb  + (size_t)2 * HDIM * SEQ;               // [1024][640]
    __bf16* WoT   = WqkvT + (size_t)1024 * HIDDEN;               // [640][640]
    // total 23.1 MB

    convert_bf16<<<dim3(SEQ * HIDDEN / 4 / 256), dim3(256), 0, stream>>>(
        x, xb, SEQ * HIDDEN / 4);
    transpose_convert<<<dim3(HIDDEN / 32, HIDDEN / 32), dim3(32, 8), 0, stream>>>(
        Wq, WqkvT, HIDDEN, HIDDEN, HIDDEN);
    transpose_convert<<<dim3(160 / 32, HIDDEN / 32), dim3(32, 8), 0, stream>>>(
        Wk, WqkvT + (size_t)HIDDEN * HIDDEN, HIDDEN, 160, HIDDEN);
    transpose_convert<<<dim3(160 / 32, HIDDEN / 32), dim3(32, 8), 0, stream>>>(
        Wv, WqkvT + (size_t)800 * HIDDEN, HIDDEN, 160, HIDDEN);
    transpose_convert<<<dim3(HIDDEN / 32, HIDDEN / 32), dim3(32, 8), 0, stream>>>(
        Wo, WoT, HIDDEN, HIDDEN, HIDDEN);

    // QKV projection -> bf16 panel
    gemm_bf16_mfma<__bf16><<<dim3(8, SEQ / 128), dim3(512), 0, stream>>>(
        xb, WqkvT, qkvb, SEQ, 960, HIDDEN, 960);

    // RMSNorm + RoPE -> qb (scaled), kb
    norm_rope_kernel<<<dim3(SEQ, NH + NKV), dim3(128), 0, stream>>>(
        (const unsigned short*)qkvb, cosb, sinb, qw, kw, qb, kb);

    // V transpose -> vtb
    v_transpose<<<dim3(SEQ / 32, 160 / 32), dim3(32, 8), 0, stream>>>(
        (const unsigned short*)qkvb, (unsigned short*)vtb);

    // MFMA flash attention -> attnb (aliases xb, dead after QKV GEMM)
    flash_attn_mfma<<<dim3(SEQ / BQ, NH), dim3(256), 0, stream>>>(
        qb, kb, vtb, xb);

    // out projection
    gemm_bf16_mfma<float><<<dim3(HIDDEN / 128, SEQ / 128), dim3(512), 0, stream>>>(
        xb, WoT, out, SEQ, HIDDEN, HIDDEN, HIDDEN);
}

// Round 8
// 87.358 us; speedup vs baseline: 36.2773x; 1.0942x over previous
//
#include <hip/hip_runtime.h>
#include <hip/hip_bf16.h>
#include <stdint.h>

#define SEQ     4096
#define HIDDEN  640
#define HDIM    80
#define NH      8
#define NKV     2
#define WINDOW  512
#define SINK    4
#define BQ      64
#define BK      64
#define KSTR    104   // Ks row stride (bf16): 2-way banks on b128 reads
#define VSTR    72    // Vt/Pl row stride (bf16): 2-way banks

typedef __bf16 bf16x8 __attribute__((ext_vector_type(8)));
typedef float  f32x4  __attribute__((ext_vector_type(4)));

__device__ inline __bf16 f2bf(float f) {
    union { float f; uint32_t u; } x; x.f = f;
    uint32_t r = x.u + 0x7FFF + ((x.u >> 16) & 1);   // RNE, no NaN inputs
    union { unsigned short s; __bf16 b; } y; y.s = (unsigned short)(r >> 16);
    return y.b;
}
__device__ inline float bf2f(unsigned short u) {
    union { uint32_t u; float f; } c; c.u = ((uint32_t)u) << 16; return c.f;
}
__device__ inline float fexp2(float x) {
#if __has_builtin(__builtin_amdgcn_exp2f)
    return __builtin_amdgcn_exp2f(x);
#else
    return exp2f(x);
#endif
}

// ---------------------------------------------------------------------------
// fp32 -> bf16 elementwise
// ---------------------------------------------------------------------------
__global__ __launch_bounds__(256) void convert_bf16(
    const float* __restrict__ src, __bf16* __restrict__ dst, int n4)
{
    int i = blockIdx.x * 256 + threadIdx.x;
    if (i >= n4) return;
    const float4 v = *(const float4*)&src[4 * i];
    dst[4 * i + 0] = f2bf(v.x);
    dst[4 * i + 1] = f2bf(v.y);
    dst[4 * i + 2] = f2bf(v.z);
    dst[4 * i + 3] = f2bf(v.w);
}

// ---------------------------------------------------------------------------
// All weight transposes in ONE launch. 1000 blocks of (32,8):
//   [0,400)   Wq -> WqkvT rows   0..639
//   [400,500) Wk -> WqkvT rows 640..799
//   [500,600) Wv -> WqkvT rows 800..959
//   [600,1000)Wo -> WoT   rows   0..639
// All sources are [640][N] f32; dst[n][k] = (bf16) src[k][n], dst_ld = 640.
// ---------------------------------------------------------------------------
__global__ __launch_bounds__(256) void weight_prep(
    const float* __restrict__ Wq, const float* __restrict__ Wk,
    const float* __restrict__ Wv, const float* __restrict__ Wo,
    __bf16* __restrict__ WqkvT, __bf16* __restrict__ WoT)
{
    const int flat = blockIdx.x;
    const float* src;
    __bf16* dstb;
    int idx, tiles_x, N;
    if (flat < 400)      { src = Wq; dstb = WqkvT;                 idx = flat;       tiles_x = 20; N = 640; }
    else if (flat < 500) { src = Wk; dstb = WqkvT + 640 * 640;     idx = flat - 400; tiles_x = 5;  N = 160; }
    else if (flat < 600) { src = Wv; dstb = WqkvT + 800 * 640;     idx = flat - 500; tiles_x = 5;  N = 160; }
    else                 { src = Wo; dstb = WoT;                   idx = flat - 600; tiles_x = 20; N = 640; }
    const int n0 = (idx % tiles_x) * 32;
    const int k0 = (idx / tiles_x) * 32;

    __shared__ float t[32][33];
    const int tx = threadIdx.x, ty = threadIdx.y;
    #pragma unroll
    for (int i = 0; i < 4; ++i) {
        int r = ty + 8 * i;
        t[r][tx] = src[(size_t)(k0 + r) * N + n0 + tx];
    }
    __syncthreads();
    #pragma unroll
    for (int i = 0; i < 4; ++i) {
        int r = ty + 8 * i;
        dstb[(size_t)(n0 + r) * 640 + k0 + tx] = f2bf(t[tx][r]);
    }
}

// ---------------------------------------------------------------------------
// MFMA bf16 GEMM (unchanged from round 7 — verified).
// ---------------------------------------------------------------------------
template <typename OutT>
__global__ __launch_bounds__(512) void gemm_bf16_mfma(
    const __bf16* __restrict__ A, const __bf16* __restrict__ BT,
    OutT* __restrict__ C, int M, int N, int K, int ldc)
{
    __shared__ __bf16 As[2][128][40];
    __shared__ __bf16 Bs[2][128][40];
    const int BUFE = 128 * 40;

    const int tid  = threadIdx.x;
    const int wave = tid >> 6;
    const int lane = tid & 63;
    const int wr = wave >> 2, wc = wave & 3;
    const int l15 = lane & 15, lq = lane >> 4;
    const int m0 = blockIdx.y * 128, n0 = blockIdx.x * 128;

    f32x4 acc[4][2];
    #pragma unroll
    for (int m = 0; m < 4; ++m)
        #pragma unroll
        for (int n = 0; n < 2; ++n) acc[m][n] = (f32x4)0.0f;

    const int sArr  = tid >> 8;
    const int sc    = tid & 255;
    const int srow  = sc >> 1;
    const int shalf = sc & 1;
    const __bf16* gsrc = sArr ? BT : A;
    const int     grow = sArr ? n0 : m0;
    const size_t  g0   = (size_t)(grow + srow) * K + 16 * shalf;
    __bf16* ldst = (sArr ? &Bs[0][0][0] : &As[0][0][0]) + srow * 40 + 16 * shalf;

    bf16x8 rg0 = *(const bf16x8*)&gsrc[g0];
    bf16x8 rg1 = *(const bf16x8*)&gsrc[g0 + 8];
    *(bf16x8*)ldst       = rg0;
    *(bf16x8*)(ldst + 8) = rg1;
    __syncthreads();

    const int nk = K >> 5;
    for (int ks = 0; ks < nk; ++ks) {
        const int cur = ks & 1;
        if (ks + 1 < nk) {
            rg0 = *(const bf16x8*)&gsrc[g0 + (size_t)(ks + 1) * 32];
            rg1 = *(const bf16x8*)&gsrc[g0 + (size_t)(ks + 1) * 32 + 8];
        }

        bf16x8 af[4], bfr[2];
        #pragma unroll
        for (int m = 0; m < 4; ++m)
            af[m] = *(const bf16x8*)&As[cur][wr * 64 + m * 16 + l15][8 * lq];
        #pragma unroll
        for (int n = 0; n < 2; ++n)
            bfr[n] = *(const bf16x8*)&Bs[cur][wc * 32 + n * 16 + l15][8 * lq];

        __builtin_amdgcn_s_setprio(1);
        #pragma unroll
        for (int m = 0; m < 4; ++m)
            #pragma unroll
            for (int n = 0; n < 2; ++n)
                acc[m][n] = __builtin_amdgcn_mfma_f32_16x16x32_bf16(af[m], bfr[n], acc[m][n], 0, 0, 0);
        __builtin_amdgcn_s_setprio(0);

        if (ks + 1 < nk) {
            *(bf16x8*)(ldst + (cur ^ 1) * BUFE)     = rg0;
            *(bf16x8*)(ldst + (cur ^ 1) * BUFE + 8) = rg1;
        }
        __syncthreads();
    }

    #pragma unroll
    for (int m = 0; m < 4; ++m) {
        #pragma unroll
        for (int n = 0; n < 2; ++n) {
            const int col = n0 + wc * 32 + n * 16 + l15;
            if (col < N) {
                const int rbase = m0 + wr * 64 + m * 16 + 4 * lq;
                #pragma unroll
                for (int r = 0; r < 4; ++r) {
                    if constexpr (sizeof(OutT) == 2)
                        C[(size_t)(rbase + r) * ldc + col] = f2bf(acc[m][n][r]);
                    else
                        C[(size_t)(rbase + r) * ldc + col] = acc[m][n][r];
                }
            }
        }
    }
}

// ---------------------------------------------------------------------------
// RMSNorm + RoPE: ONE block per row, 10 heads looped. 128 threads.
// Q heads -> qb pre-scaled by (1/sqrt(80))*log2(e) for exp2-domain softmax.
// RoPE pairing via shfl_xor(.,1); cos/sin/weights hoisted to registers.
// ---------------------------------------------------------------------------
__global__ __launch_bounds__(128) void norm_rope_kernel(
    const unsigned short* __restrict__ qkvb, const float* __restrict__ cosb,
    const float* __restrict__ sinb, const float* __restrict__ qw,
    const float* __restrict__ kw, __bf16* __restrict__ qb,
    __bf16* __restrict__ kb)
{
    const int row = blockIdx.x;
    const int tid = threadIdx.x;
    __shared__ float red[2];

    float c = 0.f, s = 0.f, wqv = 0.f, wkv = 0.f;
    if (tid < HDIM) {
        c   = cosb[(size_t)row * (HDIM / 2) + (tid >> 1)];
        s   = sinb[(size_t)row * (HDIM / 2) + (tid >> 1)];
        wqv = qw[tid];
        wkv = kw[tid];
    }
    const float sgn = (tid & 1) ? 1.0f : -1.0f;
    const float QSCALE = 0.11180339887498948f * 1.4426950408889634f;

    for (int hh = 0; hh < 10; ++hh) {
        const unsigned short* p = (hh < NH)
            ? qkvb + (size_t)row * 960 + hh * HDIM
            : qkvb + (size_t)row * 960 + HIDDEN + (hh - NH) * HDIM;
        float v = (tid < HDIM) ? bf2f(p[tid]) : 0.0f;
        float sq = v * v;
        #pragma unroll
        for (int off = 32; off; off >>= 1) sq += __shfl_down(sq, off);
        if ((tid & 63) == 0) red[tid >> 6] = sq;
        __syncthreads();
        float rms = rsqrtf((red[0] + red[1]) * (1.0f / HDIM) + 1e-5f);

        float w  = (hh < NH) ? wqv : wkv;
        float vn = v * rms * w;
        float vp = __shfl_xor(vn, 1);
        float o  = vn * c + sgn * vp * s;   // even: vn*c - vp*s ; odd: vn*c + vp*s

        if (tid < HDIM) {
            if (hh < NH) qb[(size_t)row * HIDDEN + hh * HDIM + tid] = (__bf16)(o * QSCALE);
            else         kb[(size_t)row * (NKV * HDIM) + (hh - NH) * HDIM + tid] = (__bf16)o;
        }
        __syncthreads();   // red reuse guard
    }
}

// ---------------------------------------------------------------------------
// V transpose: vtb[kvh][d][seq] = panel v cols (bf16 bit copy).
// ---------------------------------------------------------------------------
__global__ __launch_bounds__(256) void v_transpose(
    const unsigned short* __restrict__ qkvb, unsigned short* __restrict__ vtb)
{
    __shared__ unsigned short t[32][33];
    const int s0 = blockIdx.x * 32;
    const int c0 = blockIdx.y * 32;
    const int tx = threadIdx.x, ty = threadIdx.y;
    #pragma unroll
    for (int i = 0; i < 4; ++i)
        t[ty + 8 * i][tx] = qkvb[(size_t)(s0 + ty + 8 * i) * 960 + 800 + c0 + tx];
    __syncthreads();
    #pragma unroll
    for (int i = 0; i < 4; ++i) {
        int g = c0 + ty + 8 * i;           // 0..159
        int kvh = g / HDIM, d = g % HDIM;
        vtb[((size_t)kvh * HDIM + d) * SEQ + s0 + tx] = t[tx][ty + 8 * i];
    }
}

// ---------------------------------------------------------------------------
// MFMA flash attention v3: SINGLE-buffered Ks/Vt (34 KB LDS -> 4 blk/CU),
// 2 barriers/tile, reg-prefetch of next tile, exp2-domain softmax with
// exact skip-rescale. qb pre-scaled by scale*log2e. Output bf16.
// Schedule: S -> bar1 -> write K(t+1) -> softmax -> PV -> bar2 -> write V(t+1)
// ---------------------------------------------------------------------------
__global__ __launch_bounds__(256) void flash_attn_mfma(
    const __bf16* __restrict__ qb, const __bf16* __restrict__ kb,
    const __bf16* __restrict__ vtb, __bf16* __restrict__ attnb)
{
    const int i0   = blockIdx.x * BQ;
    const int h    = blockIdx.y;
    const int kvh  = h >> 2;
    const int tid  = threadIdx.x;
    const int w    = tid >> 6;
    const int lane = tid & 63;
    const int l15  = lane & 15;
    const int lq   = lane >> 4;

    __shared__ __bf16 Ks[BK][KSTR];      // 13312 B
    __shared__ __bf16 Vt[HDIM][VSTR];    // 11520 B
    __shared__ __bf16 Pl[BQ][VSTR];      //  9216 B   (34048 B -> 4 blk/CU)

    // zero K pad columns 80..95 (never rewritten)
    if (tid < 128) {
        int r = tid >> 1, c = HDIM + 8 * (tid & 1);
        *(float4*)&Ks[r][c] = make_float4(0.f, 0.f, 0.f, 0.f);
    }

    // per-thread staging descriptors (chunk = tid + 256*i, 640 chunks each)
    int koff[3], voff[3];
    bool act[3];
    #pragma unroll
    for (int i = 0; i < 3; ++i) {
        int c = tid + 256 * i;
        act[i] = (c < 640);
        int cc = act[i] ? c : 0;
        koff[i] = (cc / 10) * (NKV * HDIM) + 8 * (cc % 10);
        voff[i] = (cc >> 3) * SEQ + 8 * (cc & 7);
    }
    const __bf16* kbase = kb + kvh * HDIM;
    const __bf16* vbase = vtb + (size_t)kvh * HDIM * SEQ;
    __bf16* ksdst[3];
    __bf16* vsdst[3];
    #pragma unroll
    for (int i = 0; i < 3; ++i) {
        int cc = act[i] ? (tid + 256 * i) : 0;
        ksdst[i] = &Ks[cc / 10][8 * (cc % 10)];
        vsdst[i] = &Vt[cc >> 3][8 * (cc & 7)];
    }

    // preload Q A-fragments (wave-private rows i0+16w+l15)
    bf16x8 qf[3];
    {
        const __bf16* qrow = qb + (size_t)(i0 + 16 * w + l15) * HIDDEN + h * HDIM;
        #pragma unroll
        for (int ks = 0; ks < 3; ++ks) {
            int off = 32 * ks + 8 * lq;
            if (off >= HDIM) off = 0;     // dummy: multiplied by zeroed K pad
            qf[ks] = *(const bf16x8*)&qrow[off];
        }
    }

    float m_i[4], l_i[4];
    f32x4 o[5];
    #pragma unroll
    for (int r = 0; r < 4; ++r) { m_i[r] = -1e30f; l_i[r] = 0.0f; }
    #pragma unroll
    for (int n = 0; n < 5; ++n) o[n] = (f32x4)0.0f;

    const int w_lo   = i0 - (WINDOW - 1);
    const int w_tile = (w_lo <= 0) ? 0 : (w_lo & ~(BK - 1));
    const int n_win  = (i0 - w_tile) / BK + 1;
    const int n_tiles = n_win + ((w_tile > 0) ? 1 : 0);

    // prologue: stage tile 0
    bf16x8 krg[3], vrg[3];
    #pragma unroll
    for (int i = 0; i < 3; ++i) {
        if (act[i]) {
            krg[i] = *(const bf16x8*)&kbase[(size_t)w_tile * (NKV * HDIM) + koff[i]];
            vrg[i] = *(const bf16x8*)&vbase[(size_t)w_tile + voff[i]];
        }
    }
    #pragma unroll
    for (int i = 0; i < 3; ++i) {
        if (act[i]) {
            *(bf16x8*)ksdst[i] = krg[i];
            *(bf16x8*)vsdst[i] = vrg[i];
        }
    }
    __syncthreads();

    for (int t = 0; t < n_tiles; ++t) {
        const int j0 = (t < n_win) ? (w_tile + t * BK) : 0;
        const bool more = (t + 1 < n_tiles);

        // ---- prefetch next tile into registers (hides under S+softmax) ----
        if (more) {
            const int j1 = (t + 1 < n_win) ? (w_tile + (t + 1) * BK) : 0;
            #pragma unroll
            for (int i = 0; i < 3; ++i) {
                if (act[i]) {
                    krg[i] = *(const bf16x8*)&kbase[(size_t)j1 * (NKV * HDIM) + koff[i]];
                    vrg[i] = *(const bf16x8*)&vbase[(size_t)j1 + voff[i]];
                }
            }
        }

        // ---- S = Q K^T : 12 MFMA ----
        f32x4 sacc[4];
        #pragma unroll
        for (int n = 0; n < 4; ++n) sacc[n] = (f32x4)0.0f;
        __builtin_amdgcn_s_setprio(1);
        #pragma unroll
        for (int ks = 0; ks < 3; ++ks) {
            #pragma unroll
            for (int n = 0; n < 4; ++n) {
                bf16x8 kf = *(const bf16x8*)&Ks[n * 16 + l15][32 * ks + 8 * lq];
                sacc[n] = __builtin_amdgcn_mfma_f32_16x16x32_bf16(qf[ks], kf, sacc[n], 0, 0, 0);
            }
        }
        __builtin_amdgcn_s_setprio(0);

        __syncthreads();                    // barrier1: all S reads of Ks done
        if (more) {                         // write-early K(t+1)
            #pragma unroll
            for (int i = 0; i < 3; ++i)
                if (act[i]) *(bf16x8*)ksdst[i] = krg[i];
        }

        // ---- mask ----
        const bool full = (j0 >= i0 - 448) && (j0 <= i0 - 64);
        if (!full) {
            #pragma unroll
            for (int n = 0; n < 4; ++n) {
                int j = j0 + 16 * n + l15;
                #pragma unroll
                for (int r = 0; r < 4; ++r) {
                    int i = i0 + 16 * w + 4 * lq + r;
                    bool allowed = (j <= i) && ((j >= i - (WINDOW - 1)) || (j < SINK));
                    if (!allowed) sacc[n][r] = -1e30f;
                }
            }
        }

        // ---- online softmax (exp2 domain, exact skip-rescale) ----
        #pragma unroll
        for (int r = 0; r < 4; ++r) {
            float rmax = fmaxf(fmaxf(sacc[0][r], sacc[1][r]), fmaxf(sacc[2][r], sacc[3][r]));
            rmax = fmaxf(rmax, __shfl_xor(rmax, 1));
            rmax = fmaxf(rmax, __shfl_xor(rmax, 2));
            rmax = fmaxf(rmax, __shfl_xor(rmax, 4));
            rmax = fmaxf(rmax, __shfl_xor(rmax, 8));
            if (rmax > m_i[r]) {            // uniform within each 16-lane group
                float alpha = fexp2(m_i[r] - rmax);
                m_i[r] = rmax;
                l_i[r] *= alpha;
                #pragma unroll
                for (int n = 0; n < 5; ++n) o[n][r] *= alpha;
            }
            float rsum = 0.0f;
            #pragma unroll
            for (int n = 0; n < 4; ++n) {
                float pe = fexp2(sacc[n][r] - m_i[r]);
                Pl[16 * w + 4 * lq + r][16 * n + l15] = (__bf16)pe;
                rsum += pe;
            }
            rsum += __shfl_xor(rsum, 1);
            rsum += __shfl_xor(rsum, 2);
            rsum += __shfl_xor(rsum, 4);
            rsum += __shfl_xor(rsum, 8);
            l_i[r] += rsum;
        }

        // ---- O += P V : wave-private P rows, 10 MFMA ----
        __builtin_amdgcn_s_setprio(1);
        #pragma unroll
        for (int ks = 0; ks < 2; ++ks) {
            bf16x8 pf = *(const bf16x8*)&Pl[16 * w + l15][32 * ks + 8 * lq];
            #pragma unroll
            for (int n = 0; n < 5; ++n) {
                bf16x8 vf = *(const bf16x8*)&Vt[16 * n + l15][32 * ks + 8 * lq];
                o[n] = __builtin_amdgcn_mfma_f32_16x16x32_bf16(pf, vf, o[n], 0, 0, 0);
            }
        }
        __builtin_amdgcn_s_setprio(0);

        __syncthreads();                    // barrier2: all PV reads of Vt done
        if (more) {                         // write V(t+1)
            #pragma unroll
            for (int i = 0; i < 3; ++i)
                if (act[i]) *(bf16x8*)vsdst[i] = vrg[i];
        }
    }

    // ---- epilogue ----
    #pragma unroll
    for (int r = 0; r < 4; ++r) {
        float inv = 1.0f / l_i[r];
        int row = i0 + 16 * w + 4 * lq + r;
        #pragma unroll
        for (int n = 0; n < 5; ++n)
            attnb[(size_t)row * HIDDEN + h * HDIM + 16 * n + l15] = (__bf16)(o[n][r] * inv);
    }
}

// ---------------------------------------------------------------------------
extern "C" void kernel_launch(void* const* d_in, const int* in_sizes, int n_in,
                              void* d_out, int out_size, void* d_ws, size_t ws_size,
                              hipStream_t stream)
{
    const float* x    = (const float*)d_in[0];
    const float* cosb = (const float*)d_in[1];
    const float* sinb = (const float*)d_in[2];
    const float* Wq   = (const float*)d_in[3];
    const float* Wk   = (const float*)d_in[4];
    const float* Wv   = (const float*)d_in[5];
    const float* Wo   = (const float*)d_in[6];
    const float* qw   = (const float*)d_in[7];
    const float* kw   = (const float*)d_in[8];
    float* out = (float*)d_out;

    char* ws = (char*)d_ws;
    __bf16* qkvb  = (__bf16*)ws;                                 // [4096][960]
    __bf16* xb    = qkvb + (size_t)SEQ * 960;                    // [4096][640] -> attnb
    __bf16* qb    = xb   + (size_t)SEQ * HIDDEN;                 // [4096][640]
    __bf16* kb    = qb   + (size_t)SEQ * HIDDEN;                 // [4096][160]
    __bf16* vtb   = kb   + (size_t)SEQ * 160;                    // [2][80][4096]
    __bf16* WqkvT = vtb  + (size_t)2 * HDIM * SEQ;               // [1024][640]
    __bf16* WoT   = WqkvT + (size_t)1024 * HIDDEN;               // [640][640]

    convert_bf16<<<dim3(SEQ * HIDDEN / 4 / 256), dim3(256), 0, stream>>>(
        x, xb, SEQ * HIDDEN / 4);
    weight_prep<<<dim3(1000), dim3(32, 8), 0, stream>>>(
        Wq, Wk, Wv, Wo, WqkvT, WoT);

    // QKV projection -> bf16 panel
    gemm_bf16_mfma<__bf16><<<dim3(8, SEQ / 128), dim3(512), 0, stream>>>(
        xb, WqkvT, qkvb, SEQ, 960, HIDDEN, 960);

    // RMSNorm + RoPE -> qb (scaled by 1/sqrt(80)*log2e), kb
    norm_rope_kernel<<<dim3(SEQ), dim3(128), 0, stream>>>(
        (const unsigned short*)qkvb, cosb, sinb, qw, kw, qb, kb);

    // V transpose -> vtb
    v_transpose<<<dim3(SEQ / 32, 160 / 32), dim3(32, 8), 0, stream>>>(
        (const unsigned short*)qkvb, (unsigned short*)vtb);

    // flash attention -> attnb (aliases xb, dead after QKV GEMM)
    flash_attn_mfma<<<dim3(SEQ / BQ, NH), dim3(256), 0, stream>>>(
        qb, kb, vtb, xb);

    // out projection
    gemm_bf16_mfma<float><<<dim3(HIDDEN / 128, SEQ / 128), dim3(512), 0, stream>>>(
        xb, WoT, out, SEQ, HIDDEN, HIDDEN, HIDDEN);
}